// Round 1
// baseline (4713.250 us; speedup 1.0000x reference)
//
#include <hip/hip_runtime.h>
#include <math.h>

#define BB    2
#define LL    2048
#define DIM   1024
#define NH    16
#define DHD   64
#define NPER  16
#define NMEM  64
#define PFX   80      // NPER + NMEM
#define SS    2128    // PFX + LL

// ---------------------------------------------------------------------------
// GEMM: C[m][n] = sum_k X[m][k] * W[n][k]   (i.e. X @ W^T), K = N = 1024
// MODE 0: K-projection  -> out (B,H,S,DH), RoPE for s >= PFX
// MODE 1: V-projection  -> out (B,H,S,DH), no RoPE
// MODE 2: Q-projection  -> out (B,H,L,DH), only s >= PFX, RoPE
// MODE 3: final ctx @ Wo^T -> out (B*L, DIM) plain row-major
// ---------------------------------------------------------------------------
template <int MODE>
__global__ __launch_bounds__(256)
void gemm_kernel(const float* __restrict__ Xp,
                 const float* __restrict__ Pp,
                 const float* __restrict__ Mp,
                 const float* __restrict__ W,
                 float* __restrict__ out)
{
    const int Mtot = (MODE == 3) ? (BB * LL) : (BB * SS);
    const int bm = blockIdx.x * 128;
    const int bn = blockIdx.y * 128;

    __shared__ float Xs[16][132];   // [k][m], row stride 132 floats (16B-aligned rows)
    __shared__ float Ws[16][132];   // [k][n]

    const int tid = threadIdx.x;
    const int tm = tid & 15;
    const int tn = tid >> 4;

    float acc[8][8];
#pragma unroll
    for (int i = 0; i < 8; ++i)
#pragma unroll
        for (int j = 0; j < 8; ++j) acc[i][j] = 0.f;

    for (int k0 = 0; k0 < DIM; k0 += 16) {
        // ---- stage X tile (128 rows x 16 k) ----
#pragma unroll
        for (int i = 0; i < 2; ++i) {
            int idx = tid + i * 256;       // 0..511
            int row = idx >> 2;            // 0..127
            int kc  = idx & 3;             // 0..3 (float4 column)
            int m = bm + row;
            float4 val = make_float4(0.f, 0.f, 0.f, 0.f);
            if (m < Mtot) {
                const float* src;
                if (MODE == 3) {
                    src = Xp + (size_t)m * DIM;
                } else {
                    int b = m / SS;
                    int s = m - b * SS;
                    if (s < NPER)     src = Pp + ((size_t)b * NPER + s) * DIM;
                    else if (s < PFX) src = Mp + ((size_t)b * NMEM + (s - NPER)) * DIM;
                    else              src = Xp + ((size_t)b * LL + (s - PFX)) * DIM;
                }
                val = *reinterpret_cast<const float4*>(src + k0 + kc * 4);
            }
            Xs[kc * 4 + 0][row] = val.x;
            Xs[kc * 4 + 1][row] = val.y;
            Xs[kc * 4 + 2][row] = val.z;
            Xs[kc * 4 + 3][row] = val.w;
        }
        // ---- stage W tile (128 n-rows x 16 k) ----
#pragma unroll
        for (int i = 0; i < 2; ++i) {
            int idx = tid + i * 256;
            int row = idx >> 2;
            int kc  = idx & 3;
            float4 val = *reinterpret_cast<const float4*>(
                W + (size_t)(bn + row) * DIM + k0 + kc * 4);
            Ws[kc * 4 + 0][row] = val.x;
            Ws[kc * 4 + 1][row] = val.y;
            Ws[kc * 4 + 2][row] = val.z;
            Ws[kc * 4 + 3][row] = val.w;
        }
        __syncthreads();

#pragma unroll
        for (int k = 0; k < 16; ++k) {
            float4 a0 = *reinterpret_cast<const float4*>(&Xs[k][tm * 4]);
            float4 a1 = *reinterpret_cast<const float4*>(&Xs[k][tm * 4 + 64]);
            float4 b0 = *reinterpret_cast<const float4*>(&Ws[k][tn * 4]);
            float4 b1 = *reinterpret_cast<const float4*>(&Ws[k][tn * 4 + 64]);
            float av[8] = {a0.x, a0.y, a0.z, a0.w, a1.x, a1.y, a1.z, a1.w};
            float bv[8] = {b0.x, b0.y, b0.z, b0.w, b1.x, b1.y, b1.z, b1.w};
#pragma unroll
            for (int i = 0; i < 8; ++i)
#pragma unroll
                for (int j = 0; j < 8; ++j)
                    acc[i][j] = fmaf(av[i], bv[j], acc[i][j]);
        }
        __syncthreads();
    }

    // ---- epilogue ----
#pragma unroll
    for (int i = 0; i < 8; ++i) {
        int m = bm + ((i < 4) ? (tm * 4 + i) : (64 + tm * 4 + i - 4));
        if (m >= Mtot) continue;
        if (MODE == 3) {
#pragma unroll
            for (int j = 0; j < 8; ++j) {
                int n = bn + ((j < 4) ? (tn * 4 + j) : (64 + tn * 4 + j - 4));
                out[(size_t)m * DIM + n] = acc[i][j];
            }
        } else {
            int b = m / SS;
            int s = m - b * SS;
            if (MODE == 2 && s < PFX) continue;
            const bool rope = (MODE != 1) && (s >= PFX);
            const float pos = (float)(s - PFX);
#pragma unroll
            for (int g = 0; g < 2; ++g) {
                float vals[4];
#pragma unroll
                for (int jj = 0; jj < 4; ++jj) vals[jj] = acc[i][g * 4 + jj];
                int nbase = bn + tn * 4 + g * 64;   // multiple of 4 -> pairs in-thread
                if (rope) {
#pragma unroll
                    for (int p = 0; p < 2; ++p) {
                        int dh = (nbase + p * 2) & 63;          // even
                        // inv_freq = 10000^(-(dh/2)/32) = 2^(-(dh/2)*log2(10000)/32)
                        float fr = pos * exp2f(-(float)(dh >> 1) * 0.41524101186092029f);
                        float sn, cs;
                        sincosf(fr, &sn, &cs);
                        float x0 = vals[p * 2], x1 = vals[p * 2 + 1];
                        vals[p * 2]     = x0 * cs - x1 * sn;
                        vals[p * 2 + 1] = x0 * sn + x1 * cs;
                    }
                }
#pragma unroll
                for (int jj = 0; jj < 4; ++jj) {
                    int n = nbase + jj;
                    int h = n >> 6, dh = n & 63;
                    size_t off;
                    if (MODE == 2) off = (((size_t)b * NH + h) * LL + (s - PFX)) * DHD + dh;
                    else           off = (((size_t)b * NH + h) * SS + s) * DHD + dh;
                    out[off] = vals[jj];
                }
            }
        }
    }
}

// ---------------------------------------------------------------------------
// Attention: one block per (b, h, q-row). 256 threads stride over valid keys
// (mask is contiguous: j in [0, PFX + qi]). Per-thread online softmax with a
// 64-float register accumulator, then block-wide combine.
// ---------------------------------------------------------------------------
__global__ __launch_bounds__(256)
void attn_kernel(const float* __restrict__ q,
                 const float* __restrict__ kbuf,
                 const float* __restrict__ vbuf,
                 float* __restrict__ ctx)
{
    const int idx = blockIdx.x;
    const int qi = idx & (LL - 1);
    const int h  = (idx >> 11) & (NH - 1);
    const int b  = idx >> 15;
    const int tid = threadIdx.x;

    __shared__ float4 qs[16];
    __shared__ float  red[256];
    __shared__ float4 osum[4][16];
    __shared__ float  lsh[4];

    const float4* q4 = reinterpret_cast<const float4*>(
        q + (((size_t)b * NH + h) * LL + qi) * DHD);
    const float4* k4 = reinterpret_cast<const float4*>(
        kbuf + ((size_t)b * NH + h) * SS * DHD);
    const float4* v4 = reinterpret_cast<const float4*>(
        vbuf + ((size_t)b * NH + h) * SS * DHD);

    if (tid < 16) qs[tid] = q4[tid];
    __syncthreads();

    const int jmax = PFX + qi + 1;
    float mcur = -INFINITY;
    float lcur = 0.f;
    float4 o[16];
#pragma unroll
    for (int c = 0; c < 16; ++c) o[c] = make_float4(0.f, 0.f, 0.f, 0.f);

    for (int j = tid; j < jmax; j += 256) {
        const float4* kr = k4 + (size_t)j * 16;
        float sc = 0.f;
#pragma unroll
        for (int c = 0; c < 16; ++c) {
            float4 kk = kr[c];
            float4 qq = qs[c];
            sc = fmaf(qq.x, kk.x, sc);
            sc = fmaf(qq.y, kk.y, sc);
            sc = fmaf(qq.z, kk.z, sc);
            sc = fmaf(qq.w, kk.w, sc);
        }
        sc *= 0.125f;   // DH^-0.5
        if (sc > mcur) {
            float f = __expf(mcur - sc);   // mcur=-inf -> 0
            lcur *= f;
#pragma unroll
            for (int c = 0; c < 16; ++c) {
                o[c].x *= f; o[c].y *= f; o[c].z *= f; o[c].w *= f;
            }
            mcur = sc;
        }
        float p = __expf(sc - mcur);
        lcur += p;
        const float4* vr = v4 + (size_t)j * 16;
#pragma unroll
        for (int c = 0; c < 16; ++c) {
            float4 vv = vr[c];
            o[c].x = fmaf(p, vv.x, o[c].x);
            o[c].y = fmaf(p, vv.y, o[c].y);
            o[c].z = fmaf(p, vv.z, o[c].z);
            o[c].w = fmaf(p, vv.w, o[c].w);
        }
    }

    // block-wide max
    red[tid] = mcur;
    __syncthreads();
    for (int s2 = 128; s2 > 0; s2 >>= 1) {
        if (tid < s2) red[tid] = fmaxf(red[tid], red[tid + s2]);
        __syncthreads();
    }
    const float Mg = red[0];
    {
        float f = __expf(mcur - Mg);   // -inf -> 0 (idle threads contribute 0)
        lcur *= f;
#pragma unroll
        for (int c = 0; c < 16; ++c) {
            o[c].x *= f; o[c].y *= f; o[c].z *= f; o[c].w *= f;
        }
    }
    // wave butterfly reduce (64 lanes)
#pragma unroll
    for (int d = 32; d > 0; d >>= 1) {
        lcur += __shfl_xor(lcur, d);
#pragma unroll
        for (int c = 0; c < 16; ++c) {
            o[c].x += __shfl_xor(o[c].x, d);
            o[c].y += __shfl_xor(o[c].y, d);
            o[c].z += __shfl_xor(o[c].z, d);
            o[c].w += __shfl_xor(o[c].w, d);
        }
    }
    const int wave = tid >> 6;
    const int lane = tid & 63;
    if (lane == 0) {
        lsh[wave] = lcur;
#pragma unroll
        for (int c = 0; c < 16; ++c) osum[wave][c] = o[c];
    }
    __syncthreads();
    if (tid < 64) {
        float Lt = lsh[0] + lsh[1] + lsh[2] + lsh[3];
        int c4 = tid >> 2, comp = tid & 3;
        float num = 0.f;
#pragma unroll
        for (int w = 0; w < 4; ++w) {
            const float* pp = reinterpret_cast<const float*>(&osum[w][c4]);
            num += pp[comp];
        }
        ctx[((size_t)b * LL + qi) * DIM + h * DHD + tid] = num / Lt;
    }
}

// ---------------------------------------------------------------------------
extern "C" void kernel_launch(void* const* d_in, const int* in_sizes, int n_in,
                              void* d_out, int out_size, void* d_ws, size_t ws_size,
                              hipStream_t stream)
{
    const float* x  = (const float*)d_in[0];
    const float* pe = (const float*)d_in[1];
    const float* me = (const float*)d_in[2];
    const float* Wq = (const float*)d_in[3];
    const float* Wk = (const float*)d_in[4];
    const float* Wv = (const float*)d_in[5];
    const float* Wo = (const float*)d_in[6];
    float* out = (float*)d_out;
    float* ws  = (float*)d_ws;

    float* qb = ws;                                   // B*H*L*DH  = 4,194,304 f
    float* kb = qb + (size_t)BB * NH * LL * DHD;      // B*H*S*DH  = 4,358,144 f
    float* vb = kb + (size_t)BB * NH * SS * DHD;      // B*H*S*DH  = 4,358,144 f
    float* cb = vb + (size_t)BB * NH * SS * DHD;      // B*L*DIM   = 4,194,304 f

    dim3 blk(256);
    dim3 gp((BB * SS + 127) / 128, DIM / 128);

    hipLaunchKernelGGL((gemm_kernel<2>), gp, blk, 0, stream, x, pe, me, Wq, qb);
    hipLaunchKernelGGL((gemm_kernel<0>), gp, blk, 0, stream, x, pe, me, Wk, kb);
    hipLaunchKernelGGL((gemm_kernel<1>), gp, blk, 0, stream, x, pe, me, Wv, vb);
    hipLaunchKernelGGL(attn_kernel, dim3(BB * NH * LL), blk, 0, stream, qb, kb, vb, cb);
    hipLaunchKernelGGL((gemm_kernel<3>), dim3((BB * LL) / 128, DIM / 128), blk, 0, stream,
                       cb, nullptr, nullptr, Wo, out);
}

// Round 2
// 1201.950 us; speedup vs baseline: 3.9213x; 3.9213x over previous
//
#include <hip/hip_runtime.h>
#include <math.h>

#define BB    2
#define LL    2048
#define DIM   1024
#define NH    16
#define DHD   64
#define NPER  16
#define NMEM  64
#define PFX   80      // NPER + NMEM
#define SS    2128    // PFX + LL

#define TQ    128
#define TK    64

// ---------------------------------------------------------------------------
// GEMM: C[m][n] = sum_k X[m][k] * W[n][k]   (i.e. X @ W^T), K = N = 1024
// MODE 0: K-projection  -> out (B,H,S,DH), RoPE for s >= PFX
// MODE 1: V-projection  -> out (B,H,S,DH), no RoPE
// MODE 2: Q-projection  -> out (B,H,L,DH), only s >= PFX, RoPE
// MODE 3: final ctx @ Wo^T -> out (B*L, DIM) plain row-major
// ---------------------------------------------------------------------------
template <int MODE>
__global__ __launch_bounds__(256)
void gemm_kernel(const float* __restrict__ Xp,
                 const float* __restrict__ Pp,
                 const float* __restrict__ Mp,
                 const float* __restrict__ W,
                 float* __restrict__ out)
{
    const int Mtot = (MODE == 3) ? (BB * LL) : (BB * SS);
    const int bm = blockIdx.x * 128;
    const int bn = blockIdx.y * 128;

    __shared__ float Xs[16][132];
    __shared__ float Ws[16][132];

    const int tid = threadIdx.x;
    const int tm = tid & 15;
    const int tn = tid >> 4;

    float acc[8][8];
#pragma unroll
    for (int i = 0; i < 8; ++i)
#pragma unroll
        for (int j = 0; j < 8; ++j) acc[i][j] = 0.f;

    for (int k0 = 0; k0 < DIM; k0 += 16) {
#pragma unroll
        for (int i = 0; i < 2; ++i) {
            int idx = tid + i * 256;
            int row = idx >> 2;
            int kc  = idx & 3;
            int m = bm + row;
            float4 val = make_float4(0.f, 0.f, 0.f, 0.f);
            if (m < Mtot) {
                const float* src;
                if (MODE == 3) {
                    src = Xp + (size_t)m * DIM;
                } else {
                    int b = m / SS;
                    int s = m - b * SS;
                    if (s < NPER)     src = Pp + ((size_t)b * NPER + s) * DIM;
                    else if (s < PFX) src = Mp + ((size_t)b * NMEM + (s - NPER)) * DIM;
                    else              src = Xp + ((size_t)b * LL + (s - PFX)) * DIM;
                }
                val = *reinterpret_cast<const float4*>(src + k0 + kc * 4);
            }
            Xs[kc * 4 + 0][row] = val.x;
            Xs[kc * 4 + 1][row] = val.y;
            Xs[kc * 4 + 2][row] = val.z;
            Xs[kc * 4 + 3][row] = val.w;
        }
#pragma unroll
        for (int i = 0; i < 2; ++i) {
            int idx = tid + i * 256;
            int row = idx >> 2;
            int kc  = idx & 3;
            float4 val = *reinterpret_cast<const float4*>(
                W + (size_t)(bn + row) * DIM + k0 + kc * 4);
            Ws[kc * 4 + 0][row] = val.x;
            Ws[kc * 4 + 1][row] = val.y;
            Ws[kc * 4 + 2][row] = val.z;
            Ws[kc * 4 + 3][row] = val.w;
        }
        __syncthreads();

#pragma unroll
        for (int k = 0; k < 16; ++k) {
            float4 a0 = *reinterpret_cast<const float4*>(&Xs[k][tm * 4]);
            float4 a1 = *reinterpret_cast<const float4*>(&Xs[k][tm * 4 + 64]);
            float4 b0 = *reinterpret_cast<const float4*>(&Ws[k][tn * 4]);
            float4 b1 = *reinterpret_cast<const float4*>(&Ws[k][tn * 4 + 64]);
            float av[8] = {a0.x, a0.y, a0.z, a0.w, a1.x, a1.y, a1.z, a1.w};
            float bv[8] = {b0.x, b0.y, b0.z, b0.w, b1.x, b1.y, b1.z, b1.w};
#pragma unroll
            for (int i = 0; i < 8; ++i)
#pragma unroll
                for (int j = 0; j < 8; ++j)
                    acc[i][j] = fmaf(av[i], bv[j], acc[i][j]);
        }
        __syncthreads();
    }

#pragma unroll
    for (int i = 0; i < 8; ++i) {
        int m = bm + ((i < 4) ? (tm * 4 + i) : (64 + tm * 4 + i - 4));
        if (m >= Mtot) continue;
        if (MODE == 3) {
#pragma unroll
            for (int j = 0; j < 8; ++j) {
                int n = bn + ((j < 4) ? (tn * 4 + j) : (64 + tn * 4 + j - 4));
                out[(size_t)m * DIM + n] = acc[i][j];
            }
        } else {
            int b = m / SS;
            int s = m - b * SS;
            if (MODE == 2 && s < PFX) continue;
            const bool rope = (MODE != 1) && (s >= PFX);
            const float pos = (float)(s - PFX);
#pragma unroll
            for (int g = 0; g < 2; ++g) {
                float vals[4];
#pragma unroll
                for (int jj = 0; jj < 4; ++jj) vals[jj] = acc[i][g * 4 + jj];
                int nbase = bn + tn * 4 + g * 64;
                if (rope) {
#pragma unroll
                    for (int p = 0; p < 2; ++p) {
                        int dh = (nbase + p * 2) & 63;
                        float fr = pos * exp2f(-(float)(dh >> 1) * 0.41524101186092029f);
                        float sn, cs;
                        sincosf(fr, &sn, &cs);
                        float x0 = vals[p * 2], x1 = vals[p * 2 + 1];
                        vals[p * 2]     = x0 * cs - x1 * sn;
                        vals[p * 2 + 1] = x0 * sn + x1 * cs;
                    }
                }
#pragma unroll
                for (int jj = 0; jj < 4; ++jj) {
                    int n = nbase + jj;
                    int h = n >> 6, dh = n & 63;
                    size_t off;
                    if (MODE == 2) off = (((size_t)b * NH + h) * LL + (s - PFX)) * DHD + dh;
                    else           off = (((size_t)b * NH + h) * SS + s) * DHD + dh;
                    out[off] = vals[jj];
                }
            }
        }
    }
}

// ---------------------------------------------------------------------------
// Flash attention, fp32 VALU. One block = 128 q-rows of one (b,h).
// Iterates TK=64 key tiles: GEMM1 (S = Q K^T, reg-tiled 8x4), online softmax
// (2 threads/row, lockstep), GEMM2 (O += P V, reg-tiled 8x4).
// LDS ~102 KB -> 1 block/CU.
// ---------------------------------------------------------------------------
__global__ __launch_bounds__(256, 1)
void attn_kernel(const float* __restrict__ q,
                 const float* __restrict__ kbuf,
                 const float* __restrict__ vbuf,
                 float* __restrict__ ctx)
{
    __shared__ float Qt[DHD][TQ + 4];   // [d][r]
    __shared__ float Kt[DHD][TK + 4];   // [d][j]
    __shared__ float Pt[TK][TQ + 4];    // [j][r]  (scores, then probabilities)
    __shared__ float Vs[TK][DHD + 4];   // [j][c]
    __shared__ float mrow[TQ], lrow[TQ], frow[TQ];

    const int tid = threadIdx.x;
    const int bh  = blockIdx.y;         // b*16 + h
    const int b   = bh >> 4;
    int qt = blockIdx.x;
    if (b) qt = 15 - qt;                // pair heavy+light q-tiles per CU
    const int q0 = qt * TQ;

    const int tr = tid & 15;
    const int tj = tid >> 4;

    // ---- stage Q (transposed) ----
    const float* qbase = q + ((size_t)bh * LL + q0) * DHD;
#pragma unroll
    for (int i = 0; i < 8; ++i) {
        int lin = tid + i * 256;        // 0..2047 float4s
        int r   = lin >> 4;
        int dq  = (lin & 15) * 4;
        float4 v = *reinterpret_cast<const float4*>(qbase + (size_t)r * DHD + dq);
        Qt[dq + 0][r] = v.x; Qt[dq + 1][r] = v.y;
        Qt[dq + 2][r] = v.z; Qt[dq + 3][r] = v.w;
    }
    if (tid < TQ) { mrow[tid] = -INFINITY; lrow[tid] = 0.f; }
    __syncthreads();

    float4 o[8];
#pragma unroll
    for (int i = 0; i < 8; ++i) o[i] = make_float4(0.f, 0.f, 0.f, 0.f);

    const float* kb0 = kbuf + (size_t)bh * SS * DHD;
    const float* vb0 = vbuf + (size_t)bh * SS * DHD;

    const int ntiles = (PFX + q0 + TQ + TK - 1) / TK;

    for (int kt = 0; kt < ntiles; ++kt) {
        const int j0 = kt * TK;

        // ---- stage K (transposed) and V ----
#pragma unroll
        for (int i = 0; i < 4; ++i) {
            int lin = tid + i * 256;    // 0..1023 float4s
            int j   = lin >> 4;
            int dq  = (lin & 15) * 4;
            int jg  = j0 + j;
            float4 kv = make_float4(0.f, 0.f, 0.f, 0.f);
            float4 vv = make_float4(0.f, 0.f, 0.f, 0.f);
            if (jg < SS) {
                kv = *reinterpret_cast<const float4*>(kb0 + (size_t)jg * DHD + dq);
                vv = *reinterpret_cast<const float4*>(vb0 + (size_t)jg * DHD + dq);
            }
            Kt[dq + 0][j] = kv.x; Kt[dq + 1][j] = kv.y;
            Kt[dq + 2][j] = kv.z; Kt[dq + 3][j] = kv.w;
            *reinterpret_cast<float4*>(&Vs[j][dq]) = vv;
        }
        __syncthreads();

        // ---- GEMM1: S[r][j] = Q . K ----
        float s[8][4];
#pragma unroll
        for (int i = 0; i < 8; ++i)
#pragma unroll
            for (int jj = 0; jj < 4; ++jj) s[i][jj] = 0.f;

#pragma unroll 8
        for (int d = 0; d < DHD; ++d) {
            float4 a0 = *reinterpret_cast<const float4*>(&Qt[d][tr * 4]);
            float4 a1 = *reinterpret_cast<const float4*>(&Qt[d][tr * 4 + 64]);
            float4 bv = *reinterpret_cast<const float4*>(&Kt[d][tj * 4]);
            float av[8] = {a0.x, a0.y, a0.z, a0.w, a1.x, a1.y, a1.z, a1.w};
            float bb[4] = {bv.x, bv.y, bv.z, bv.w};
#pragma unroll
            for (int i = 0; i < 8; ++i)
#pragma unroll
                for (int jj = 0; jj < 4; ++jj)
                    s[i][jj] = fmaf(av[i], bb[jj], s[i][jj]);
        }
        // write S (scaled) transposed: Pt[j][r]
#pragma unroll
        for (int i = 0; i < 8; ++i) {
            int r = (i < 4) ? (tr * 4 + i) : (64 + tr * 4 + i - 4);
#pragma unroll
            for (int jj = 0; jj < 4; ++jj)
                Pt[tj * 4 + jj][r] = s[i][jj] * 0.125f;
        }
        __syncthreads();

        // ---- online softmax: 2 threads per row ----
        {
            const int r    = tid >> 1;
            const int half = tid & 1;
            const int jb   = half * 32;
            float mold = mrow[r];
            float sv[32];
            float mt = -INFINITY;
#pragma unroll
            for (int jj = 0; jj < 32; ++jj) {
                float x = Pt[jb + jj][r];
                if (j0 + jb + jj > PFX + q0 + r) x = -INFINITY;
                sv[jj] = x;
                mt = fmaxf(mt, x);
            }
            mt = fmaxf(mt, __shfl_xor(mt, 1));
            float mnew = fmaxf(mold, mt);
            float f = __expf(mold - mnew);      // mold=-inf -> 0
            float lsum = 0.f;
#pragma unroll
            for (int jj = 0; jj < 32; ++jj) {
                float p = __expf(sv[jj] - mnew);
                lsum += p;
                Pt[jb + jj][r] = p;
            }
            lsum += __shfl_xor(lsum, 1);
            if (half == 0) {
                mrow[r] = mnew;
                frow[r] = f;
                lrow[r] = lrow[r] * f + lsum;
            }
        }
        __syncthreads();

        // ---- GEMM2: O = O*f + P V ----
        {
            float fr_[8];
#pragma unroll
            for (int i = 0; i < 8; ++i) {
                int r = (i < 4) ? (tr * 4 + i) : (64 + tr * 4 + i - 4);
                fr_[i] = frow[r];
            }
#pragma unroll
            for (int i = 0; i < 8; ++i) {
                o[i].x *= fr_[i]; o[i].y *= fr_[i];
                o[i].z *= fr_[i]; o[i].w *= fr_[i];
            }
#pragma unroll 8
            for (int j = 0; j < TK; ++j) {
                float4 a0 = *reinterpret_cast<const float4*>(&Pt[j][tr * 4]);
                float4 a1 = *reinterpret_cast<const float4*>(&Pt[j][tr * 4 + 64]);
                float4 bv = *reinterpret_cast<const float4*>(&Vs[j][tj * 4]);
                float av[8] = {a0.x, a0.y, a0.z, a0.w, a1.x, a1.y, a1.z, a1.w};
#pragma unroll
                for (int i = 0; i < 8; ++i) {
                    o[i].x = fmaf(av[i], bv.x, o[i].x);
                    o[i].y = fmaf(av[i], bv.y, o[i].y);
                    o[i].z = fmaf(av[i], bv.z, o[i].z);
                    o[i].w = fmaf(av[i], bv.w, o[i].w);
                }
            }
        }
        __syncthreads();
    }

    // ---- epilogue: normalize and store (B, L, DIM) ----
    const int h = bh & 15;
#pragma unroll
    for (int i = 0; i < 8; ++i) {
        int r = (i < 4) ? (tr * 4 + i) : (64 + tr * 4 + i - 4);
        float inv = 1.f / lrow[r];
        float4 res = make_float4(o[i].x * inv, o[i].y * inv, o[i].z * inv, o[i].w * inv);
        *reinterpret_cast<float4*>(
            &ctx[((size_t)b * LL + q0 + r) * DIM + h * DHD + tj * 4]) = res;
    }
}

// ---------------------------------------------------------------------------
extern "C" void kernel_launch(void* const* d_in, const int* in_sizes, int n_in,
                              void* d_out, int out_size, void* d_ws, size_t ws_size,
                              hipStream_t stream)
{
    const float* x  = (const float*)d_in[0];
    const float* pe = (const float*)d_in[1];
    const float* me = (const float*)d_in[2];
    const float* Wq = (const float*)d_in[3];
    const float* Wk = (const float*)d_in[4];
    const float* Wv = (const float*)d_in[5];
    const float* Wo = (const float*)d_in[6];
    float* out = (float*)d_out;
    float* ws  = (float*)d_ws;

    float* qb = ws;
    float* kb = qb + (size_t)BB * NH * LL * DHD;
    float* vb = kb + (size_t)BB * NH * SS * DHD;
    float* cb = vb + (size_t)BB * NH * SS * DHD;

    dim3 blk(256);
    dim3 gp((BB * SS + 127) / 128, DIM / 128);

    hipLaunchKernelGGL((gemm_kernel<2>), gp, blk, 0, stream, x, pe, me, Wq, qb);
    hipLaunchKernelGGL((gemm_kernel<0>), gp, blk, 0, stream, x, pe, me, Wk, kb);
    hipLaunchKernelGGL((gemm_kernel<1>), gp, blk, 0, stream, x, pe, me, Wv, vb);
    hipLaunchKernelGGL(attn_kernel, dim3(LL / TQ, BB * NH), blk, 0, stream, qb, kb, vb, cb);
    hipLaunchKernelGGL((gemm_kernel<3>), dim3((BB * LL) / 128, DIM / 128), blk, 0, stream,
                       cb, nullptr, nullptr, Wo, out);
}

// Round 3
// 639.785 us; speedup vs baseline: 7.3669x; 1.8787x over previous
//
#include <hip/hip_runtime.h>
#include <math.h>

#define BB    2
#define LL    2048
#define DIM   1024
#define NH    16
#define DHD   64
#define NPER  16
#define NMEM  64
#define PFX   80      // NPER + NMEM
#define SS    2128    // PFX + LL
#define MQKV  (BB*SS) // 4256
#define NQKV  3072
#define MOUT  (BB*LL) // 4096

#define TQ    128
#define TK    64

typedef __attribute__((ext_vector_type(4))) float f32x4;
typedef __attribute__((ext_vector_type(8))) short bf16x8;

__device__ __forceinline__ unsigned short f2bf(float x) {
    union { float f; unsigned u; } v; v.f = x;
    unsigned r = (v.u + 0x7fffu + ((v.u >> 16) & 1u)) >> 16;
    return (unsigned short)r;
}

__device__ __forceinline__ void gload_lds16(const void* g, void* l) {
    __builtin_amdgcn_global_load_lds(
        (__attribute__((address_space(1))) void*)(g),
        (__attribute__((address_space(3))) void*)(l), 16, 0, 0);
}

// ---------------------------------------------------------------------------
// Prep: fp32 -> bf16 conversions (concat full_x, fused Wqkv, Wo) + RoPE tables
// ---------------------------------------------------------------------------
__global__ __launch_bounds__(256)
void prep_kernel(const float* __restrict__ x,  const float* __restrict__ pe,
                 const float* __restrict__ me, const float* __restrict__ Wq,
                 const float* __restrict__ Wk, const float* __restrict__ Wv,
                 const float* __restrict__ Wo,
                 unsigned short* __restrict__ xbf,    // [MQKV][DIM]
                 unsigned short* __restrict__ wqkv,   // [3072][1024]
                 unsigned short* __restrict__ wobf,   // [1024][1024]
                 float* __restrict__ ropeC, float* __restrict__ ropeS)
{
    const int nthr = gridDim.x * blockDim.x;
    const int t0   = blockIdx.x * blockDim.x + threadIdx.x;

    for (int g = t0; g < MQKV * (DIM / 4); g += nthr) {
        int d4  = g & 255;
        int row = g >> 8;
        int b   = row >= SS;
        int s   = row - b * SS;
        const float* src;
        if (s < NPER)     src = pe + ((size_t)(b * NPER + s)) * DIM;
        else if (s < PFX) src = me + ((size_t)(b * NMEM + (s - NPER))) * DIM;
        else              src = x  + ((size_t)(b * LL   + (s - PFX)))  * DIM;
        float4 v = *reinterpret_cast<const float4*>(src + d4 * 4);
        ushort4 o; o.x = f2bf(v.x); o.y = f2bf(v.y); o.z = f2bf(v.z); o.w = f2bf(v.w);
        *reinterpret_cast<ushort4*>(xbf + (size_t)g * 4) = o;
    }
    for (int g = t0; g < NQKV * (DIM / 4); g += nthr) {
        int row = g >> 8;
        const float* src = (row < 1024) ? (Wq + (size_t)row * DIM)
                         : (row < 2048) ? (Wk + (size_t)(row - 1024) * DIM)
                         :                (Wv + (size_t)(row - 2048) * DIM);
        float4 v = *reinterpret_cast<const float4*>(src + (g & 255) * 4);
        ushort4 o; o.x = f2bf(v.x); o.y = f2bf(v.y); o.z = f2bf(v.z); o.w = f2bf(v.w);
        *reinterpret_cast<ushort4*>(wqkv + (size_t)g * 4) = o;
    }
    for (int g = t0; g < DIM * (DIM / 4); g += nthr) {
        float4 v = *reinterpret_cast<const float4*>(Wo + (size_t)g * 4);
        ushort4 o; o.x = f2bf(v.x); o.y = f2bf(v.y); o.z = f2bf(v.z); o.w = f2bf(v.w);
        *reinterpret_cast<ushort4*>(wobf + (size_t)g * 4) = o;
    }
    for (int i = t0; i < LL * 32; i += nthr) {
        int pos = i >> 5, fi = i & 31;
        float ang = (float)pos * exp2f(-(float)fi * 0.41524101186092029f);
        ropeC[i] = cosf(ang);
        ropeS[i] = sinf(ang);
    }
}

// ---------------------------------------------------------------------------
// bf16 MFMA GEMM, 128x128 tile, BK=32, 256 threads (4 waves, 2x2 quadrants).
// C[m][n] = sum_k A[m][k] * Bw[n][k]  (A @ Bw^T), K = 1024.
// MODE 0: A = xfull_bf16, Bw = Wqkv -> RoPE epilogue, scatter fp32 q/k/v.
// MODE 1: A = ctx_bf16,   Bw = Wo   -> plain fp32 store.
// ---------------------------------------------------------------------------
template <int MODE>
__global__ __launch_bounds__(256)
void mfma_gemm(const unsigned short* __restrict__ A,
               const unsigned short* __restrict__ Bw,
               const float* __restrict__ ropeC, const float* __restrict__ ropeS,
               float* __restrict__ qb, float* __restrict__ kb,
               float* __restrict__ vb, float* __restrict__ outp)
{
    __shared__ short As[128 * 32] __attribute__((aligned(16)));
    __shared__ short Bs[128 * 32] __attribute__((aligned(16)));

    const int tid  = threadIdx.x;
    const int lane = tid & 63;
    const int wid  = tid >> 6;
    const int wr   = wid >> 1, wc = wid & 1;
    const int bm   = blockIdx.x * 128;
    const int bn   = blockIdx.y * 128;
    const int Mtot = (MODE == 0) ? MQKV : MOUT;

    f32x4 acc[4][4];
#pragma unroll
    for (int m = 0; m < 4; ++m)
#pragma unroll
        for (int n = 0; n < 4; ++n) acc[m][n] = (f32x4)(0.f);

    const int r0 = wid * 32 + (lane >> 2);   // staging row within tile
    const int cc = (lane & 3) * 8;           // staging k-chunk (elements)

    for (int k0 = 0; k0 < DIM; k0 += 32) {
        int ra0 = bm + r0;      if (ra0 > Mtot - 1) ra0 = Mtot - 1;
        int ra1 = bm + r0 + 16; if (ra1 > Mtot - 1) ra1 = Mtot - 1;
        gload_lds16(A + (size_t)ra0 * DIM + k0 + cc, As + wid * 1024);
        gload_lds16(A + (size_t)ra1 * DIM + k0 + cc, As + wid * 1024 + 512);
        int rb0 = bn + r0, rb1 = bn + r0 + 16;
        gload_lds16(Bw + (size_t)rb0 * DIM + k0 + cc, Bs + wid * 1024);
        gload_lds16(Bw + (size_t)rb1 * DIM + k0 + cc, Bs + wid * 1024 + 512);
        __syncthreads();

        bf16x8 af[4], bf[4];
#pragma unroll
        for (int m = 0; m < 4; ++m)
            af[m] = *reinterpret_cast<const bf16x8*>(
                As + (wr * 64 + m * 16 + (lane & 15)) * 32 + (lane >> 4) * 8);
#pragma unroll
        for (int n = 0; n < 4; ++n)
            bf[n] = *reinterpret_cast<const bf16x8*>(
                Bs + (wc * 64 + n * 16 + (lane & 15)) * 32 + (lane >> 4) * 8);
#pragma unroll
        for (int m = 0; m < 4; ++m)
#pragma unroll
            for (int n = 0; n < 4; ++n)
                acc[m][n] = __builtin_amdgcn_mfma_f32_16x16x32_bf16(
                    af[m], bf[n], acc[m][n], 0, 0, 0);
        __syncthreads();
    }

    // epilogue: C row = bm+wr*64+m*16+(lane>>4)*4+q, col = bn+wc*64+n*16+(lane&15)
    const int colb = bn + wc * 64 + (lane & 15);
    const int rowb = bm + wr * 64 + ((lane >> 4) << 2);
    const int which = bn >> 10;   // block-uniform: 0=Q 1=K 2=V (MODE 0)

#pragma unroll
    for (int m = 0; m < 4; ++m) {
#pragma unroll
        for (int n = 0; n < 4; ++n) {
            const int col = colb + n * 16;
            const int nn  = col & 1023;
            const int h   = nn >> 6;
            const int dh  = nn & 63;
#pragma unroll
            for (int qreg = 0; qreg < 4; ++qreg) {
                const int row = rowb + m * 16 + qreg;
                float val   = acc[m][n][qreg];
                float other = __shfl_xor(val, 1);   // paired RoPE column
                if (row >= Mtot) continue;
                if (MODE == 1) {
                    outp[(size_t)row * DIM + col] = val;
                } else {
                    const int b = row >= SS;
                    const int s = row - b * SS;
                    if (which == 2) {
                        vb[(((size_t)b * NH + h) * SS + s) * DHD + dh] = val;
                    } else {
                        if (s >= PFX) {
                            const int pos = s - PFX;
                            float cs = ropeC[pos * 32 + (dh >> 1)];
                            float sn = ropeS[pos * 32 + (dh >> 1)];
                            val = (dh & 1) ? (other * sn + val * cs)
                                           : (val * cs - other * sn);
                        }
                        if (which == 0) {
                            if (s >= PFX)
                                qb[(((size_t)b * NH + h) * LL + (s - PFX)) * DHD + dh] = val;
                        } else {
                            kb[(((size_t)b * NH + h) * SS + s) * DHD + dh] = val;
                        }
                    }
                }
            }
        }
    }
}

// ---------------------------------------------------------------------------
// Flash attention, fp32 VALU, 512 threads (8 waves = 2/SIMD).
// One block = 128 q-rows of one (b,h); TK=64 key tiles.
// Emits ctx as bf16 for the final MFMA GEMM.
// ---------------------------------------------------------------------------
__global__ __launch_bounds__(512)
void attn_kernel(const float* __restrict__ q,
                 const float* __restrict__ kbuf,
                 const float* __restrict__ vbuf,
                 unsigned short* __restrict__ ctx)
{
    __shared__ float Qt[DHD][TQ + 4];
    __shared__ float Kt[DHD][TK + 4];
    __shared__ float Pt[TK][TQ + 4];
    __shared__ float Vs[TK][DHD + 4];
    __shared__ float mrow[TQ], lrow[TQ], frow[TQ];

    const int tid = threadIdx.x;
    const int bh  = blockIdx.y;
    const int b   = bh >> 4;
    int qt = blockIdx.x;
    if (b) qt = 15 - qt;                 // pair heavy+light tiles
    const int q0 = qt * TQ;

    const int tr = tid & 15;             // 8 rows: tr*4..+3 and +64
    const int tc = tid >> 4;             // 0..31 -> 2 cols tc*2..+1

    const float* qbase = q + ((size_t)bh * LL + q0) * DHD;
#pragma unroll
    for (int i = 0; i < 4; ++i) {
        int lin = tid + i * 512;         // 0..2047 float4s
        int r   = lin >> 4;
        int dq  = (lin & 15) * 4;
        float4 v = *reinterpret_cast<const float4*>(qbase + (size_t)r * DHD + dq);
        Qt[dq + 0][r] = v.x; Qt[dq + 1][r] = v.y;
        Qt[dq + 2][r] = v.z; Qt[dq + 3][r] = v.w;
    }
    if (tid < TQ) { mrow[tid] = -INFINITY; lrow[tid] = 0.f; }
    __syncthreads();

    float2 o[8];
#pragma unroll
    for (int i = 0; i < 8; ++i) o[i] = make_float2(0.f, 0.f);

    const float* kb0 = kbuf + (size_t)bh * SS * DHD;
    const float* vb0 = vbuf + (size_t)bh * SS * DHD;
    const int ntiles = (PFX + q0 + TQ + TK - 1) / TK;

    for (int kt = 0; kt < ntiles; ++kt) {
        const int j0 = kt * TK;

#pragma unroll
        for (int i = 0; i < 2; ++i) {
            int lin = tid + i * 512;     // 0..1023 float4s
            int j   = lin >> 4;
            int dq  = (lin & 15) * 4;
            int jg  = j0 + j;
            float4 kv = make_float4(0.f, 0.f, 0.f, 0.f);
            float4 vv = make_float4(0.f, 0.f, 0.f, 0.f);
            if (jg < SS) {
                kv = *reinterpret_cast<const float4*>(kb0 + (size_t)jg * DHD + dq);
                vv = *reinterpret_cast<const float4*>(vb0 + (size_t)jg * DHD + dq);
            }
            Kt[dq + 0][j] = kv.x; Kt[dq + 1][j] = kv.y;
            Kt[dq + 2][j] = kv.z; Kt[dq + 3][j] = kv.w;
            *reinterpret_cast<float4*>(&Vs[j][dq]) = vv;
        }
        __syncthreads();

        // GEMM1: S[r][j], per-thread 8x2
        float s[8][2];
#pragma unroll
        for (int i = 0; i < 8; ++i) { s[i][0] = 0.f; s[i][1] = 0.f; }
#pragma unroll 8
        for (int d = 0; d < DHD; ++d) {
            float4 a0 = *reinterpret_cast<const float4*>(&Qt[d][tr * 4]);
            float4 a1 = *reinterpret_cast<const float4*>(&Qt[d][tr * 4 + 64]);
            float2 bv = *reinterpret_cast<const float2*>(&Kt[d][tc * 2]);
            float av[8] = {a0.x, a0.y, a0.z, a0.w, a1.x, a1.y, a1.z, a1.w};
#pragma unroll
            for (int i = 0; i < 8; ++i) {
                s[i][0] = fmaf(av[i], bv.x, s[i][0]);
                s[i][1] = fmaf(av[i], bv.y, s[i][1]);
            }
        }
#pragma unroll
        for (int i = 0; i < 8; ++i) {
            int r = (i < 4) ? (tr * 4 + i) : (64 + tr * 4 + i - 4);
            Pt[tc * 2 + 0][r] = s[i][0] * 0.125f;
            Pt[tc * 2 + 1][r] = s[i][1] * 0.125f;
        }
        __syncthreads();

        // online softmax: 4 threads per row
        {
            const int r   = tid >> 2;
            const int qtr = tid & 3;
            const int jb  = qtr * 16;
            float mold = mrow[r];
            float sv[16];
            float mt = -INFINITY;
#pragma unroll
            for (int jj = 0; jj < 16; ++jj) {
                float xv = Pt[jb + jj][r];
                if (j0 + jb + jj > PFX + q0 + r) xv = -INFINITY;
                sv[jj] = xv;
                mt = fmaxf(mt, xv);
            }
            mt = fmaxf(mt, __shfl_xor(mt, 1));
            mt = fmaxf(mt, __shfl_xor(mt, 2));
            float mnew = fmaxf(mold, mt);
            float f = __expf(mold - mnew);
            float lsum = 0.f;
#pragma unroll
            for (int jj = 0; jj < 16; ++jj) {
                float p = __expf(sv[jj] - mnew);
                lsum += p;
                Pt[jb + jj][r] = p;
            }
            lsum += __shfl_xor(lsum, 1);
            lsum += __shfl_xor(lsum, 2);
            if (qtr == 0) {
                mrow[r] = mnew;
                frow[r] = f;
                lrow[r] = lrow[r] * f + lsum;
            }
        }
        __syncthreads();

        // GEMM2: O = O*f + P V, per-thread 8x2
        {
            float fr_[8];
#pragma unroll
            for (int i = 0; i < 8; ++i) {
                int r = (i < 4) ? (tr * 4 + i) : (64 + tr * 4 + i - 4);
                fr_[i] = frow[r];
            }
#pragma unroll
            for (int i = 0; i < 8; ++i) { o[i].x *= fr_[i]; o[i].y *= fr_[i]; }
#pragma unroll 8
            for (int j = 0; j < TK; ++j) {
                float4 a0 = *reinterpret_cast<const float4*>(&Pt[j][tr * 4]);
                float4 a1 = *reinterpret_cast<const float4*>(&Pt[j][tr * 4 + 64]);
                float2 vv = *reinterpret_cast<const float2*>(&Vs[j][tc * 2]);
                float av[8] = {a0.x, a0.y, a0.z, a0.w, a1.x, a1.y, a1.z, a1.w};
#pragma unroll
                for (int i = 0; i < 8; ++i) {
                    o[i].x = fmaf(av[i], vv.x, o[i].x);
                    o[i].y = fmaf(av[i], vv.y, o[i].y);
                }
            }
        }
        __syncthreads();
    }

    const int h = bh & 15;
#pragma unroll
    for (int i = 0; i < 8; ++i) {
        int r = (i < 4) ? (tr * 4 + i) : (64 + tr * 4 + i - 4);
        float inv = 1.f / lrow[r];
        ushort2 t;
        t.x = f2bf(o[i].x * inv);
        t.y = f2bf(o[i].y * inv);
        *reinterpret_cast<ushort2*>(
            &ctx[((size_t)b * LL + q0 + r) * DIM + h * DHD + tc * 2]) = t;
    }
}

// ---------------------------------------------------------------------------
extern "C" void kernel_launch(void* const* d_in, const int* in_sizes, int n_in,
                              void* d_out, int out_size, void* d_ws, size_t ws_size,
                              hipStream_t stream)
{
    const float* x  = (const float*)d_in[0];
    const float* pe = (const float*)d_in[1];
    const float* me = (const float*)d_in[2];
    const float* Wq = (const float*)d_in[3];
    const float* Wk = (const float*)d_in[4];
    const float* Wv = (const float*)d_in[5];
    const float* Wo = (const float*)d_in[6];
    float* out = (float*)d_out;

    unsigned short* xbf  = (unsigned short*)d_ws;                  // 4256*1024
    unsigned short* wqkv = xbf + (size_t)MQKV * DIM;               // 3072*1024
    unsigned short* wobf = wqkv + (size_t)NQKV * DIM;              // 1024*1024
    float* ropeC = (float*)(wobf + (size_t)DIM * DIM);             // 2048*32
    float* ropeS = ropeC + LL * 32;                                // 2048*32
    float* qb    = ropeS + LL * 32;                                // B*H*L*DH
    float* kb    = qb + (size_t)BB * NH * LL * DHD;                // B*H*S*DH
    float* vb    = kb + (size_t)BB * NH * SS * DHD;                // B*H*S*DH
    unsigned short* ctx = (unsigned short*)(vb + (size_t)BB * NH * SS * DHD); // 4096*1024

    hipLaunchKernelGGL(prep_kernel, dim3(2048), dim3(256), 0, stream,
                       x, pe, me, Wq, Wk, Wv, Wo, xbf, wqkv, wobf, ropeC, ropeS);
    hipLaunchKernelGGL((mfma_gemm<0>), dim3((MQKV + 127) / 128, NQKV / 128), dim3(256), 0, stream,
                       xbf, wqkv, ropeC, ropeS, qb, kb, vb, nullptr);
    hipLaunchKernelGGL(attn_kernel, dim3(LL / TQ, BB * NH), dim3(512), 0, stream,
                       qb, kb, vb, ctx);
    hipLaunchKernelGGL((mfma_gemm<1>), dim3(MOUT / 128, DIM / 128), dim3(256), 0, stream,
                       ctx, wobf, nullptr, nullptr, nullptr, nullptr, nullptr, out);
}

// Round 5
// 176.038 us; speedup vs baseline: 26.7741x; 3.6344x over previous
//
#include <hip/hip_runtime.h>
#include <math.h>

#define BB    2
#define LL    2048
#define DIM   1024
#define NH    16
#define DHD   64
#define NPER  16
#define NMEM  64
#define PFX   80      // NPER + NMEM
#define SS    2128    // PFX + LL
#define MQKV  (BB*SS) // 4256
#define NQKV  3072
#define MOUT  (BB*LL) // 4096

typedef __attribute__((ext_vector_type(4)))  float f32x4;
typedef __attribute__((ext_vector_type(16))) float f32x16;
typedef __attribute__((ext_vector_type(8)))  short bf16x8;
typedef unsigned short u16;
typedef unsigned int   u32;

union I4B8 { int4 i; bf16x8 v; };

__device__ __forceinline__ u16 f2bf(float x) {
    union { float f; u32 u; } v; v.f = x;
    return (u16)((v.u + 0x7fffu + ((v.u >> 16) & 1u)) >> 16);
}
__device__ __forceinline__ u32 cvtpk(float lo, float hi) {
    u32 r; asm("v_cvt_pk_bf16_f32 %0, %1, %2" : "=v"(r) : "v"(lo), "v"(hi));
    return r;
}
__device__ __forceinline__ void gload_lds16(const void* g, void* l) {
    __builtin_amdgcn_global_load_lds(
        (__attribute__((address_space(1))) void*)(g),
        (__attribute__((address_space(3))) void*)(l), 16, 0, 0);
}

// ---------------------------------------------------------------------------
// Prep: fp32 -> bf16 conversions + RoPE tables
// ---------------------------------------------------------------------------
__global__ __launch_bounds__(256)
void prep_kernel(const float* __restrict__ x,  const float* __restrict__ pe,
                 const float* __restrict__ me, const float* __restrict__ Wq,
                 const float* __restrict__ Wk, const float* __restrict__ Wv,
                 const float* __restrict__ Wo,
                 u16* __restrict__ xbf, u16* __restrict__ wqkv,
                 u16* __restrict__ wobf,
                 float* __restrict__ ropeC, float* __restrict__ ropeS)
{
    const int nthr = gridDim.x * blockDim.x;
    const int t0   = blockIdx.x * blockDim.x + threadIdx.x;

    for (int g = t0; g < MQKV * (DIM / 4); g += nthr) {
        int d4  = g & 255;
        int row = g >> 8;
        int b   = row >= SS;
        int s   = row - b * SS;
        const float* src;
        if (s < NPER)     src = pe + ((size_t)(b * NPER + s)) * DIM;
        else if (s < PFX) src = me + ((size_t)(b * NMEM + (s - NPER))) * DIM;
        else              src = x  + ((size_t)(b * LL   + (s - PFX)))  * DIM;
        float4 v = *reinterpret_cast<const float4*>(src + d4 * 4);
        ushort4 o; o.x = f2bf(v.x); o.y = f2bf(v.y); o.z = f2bf(v.z); o.w = f2bf(v.w);
        *reinterpret_cast<ushort4*>(xbf + (size_t)g * 4) = o;
    }
    for (int g = t0; g < NQKV * (DIM / 4); g += nthr) {
        int row = g >> 8;
        const float* src = (row < 1024) ? (Wq + (size_t)row * DIM)
                         : (row < 2048) ? (Wk + (size_t)(row - 1024) * DIM)
                         :                (Wv + (size_t)(row - 2048) * DIM);
        float4 v = *reinterpret_cast<const float4*>(src + (g & 255) * 4);
        ushort4 o; o.x = f2bf(v.x); o.y = f2bf(v.y); o.z = f2bf(v.z); o.w = f2bf(v.w);
        *reinterpret_cast<ushort4*>(wqkv + (size_t)g * 4) = o;
    }
    for (int g = t0; g < DIM * (DIM / 4); g += nthr) {
        float4 v = *reinterpret_cast<const float4*>(Wo + (size_t)g * 4);
        ushort4 o; o.x = f2bf(v.x); o.y = f2bf(v.y); o.z = f2bf(v.z); o.w = f2bf(v.w);
        *reinterpret_cast<ushort4*>(wobf + (size_t)g * 4) = o;
    }
    for (int i = t0; i < LL * 32; i += nthr) {
        int pos = i >> 5, fi = i & 31;
        float ang = (float)pos * exp2f(-(float)fi * 0.41524101186092029f);
        ropeC[i] = cosf(ang);
        ropeS[i] = sinf(ang);
    }
}

// ---------------------------------------------------------------------------
// bf16 MFMA GEMM (m97-style 128x128 tile, BK=32, 4 waves).
// MODE 0: A=xfull, Bw=Wqkv -> RoPE epilogue, scatter bf16 q/k/v.
// MODE 1: A=ctx bf16, Bw=Wo -> fp32 out.
// ---------------------------------------------------------------------------
template <int MODE>
__global__ __launch_bounds__(256)
void mfma_gemm(const u16* __restrict__ A, const u16* __restrict__ Bw,
               const float* __restrict__ ropeC, const float* __restrict__ ropeS,
               u16* __restrict__ qb, u16* __restrict__ kb,
               u16* __restrict__ vb, float* __restrict__ outp)
{
    __shared__ short As[128 * 32] __attribute__((aligned(16)));
    __shared__ short Bs[128 * 32] __attribute__((aligned(16)));

    const int tid  = threadIdx.x;
    const int lane = tid & 63;
    const int wid  = tid >> 6;
    const int wr   = wid >> 1, wc = wid & 1;
    const int bm   = blockIdx.x * 128;
    const int bn   = blockIdx.y * 128;
    const int Mtot = (MODE == 0) ? MQKV : MOUT;

    f32x4 acc[4][4];
#pragma unroll
    for (int m = 0; m < 4; ++m)
#pragma unroll
        for (int n = 0; n < 4; ++n) acc[m][n] = (f32x4)(0.f);

    const int r0 = wid * 32 + (lane >> 2);
    const int cc = (lane & 3) * 8;

    for (int k0 = 0; k0 < DIM; k0 += 32) {
        int ra0 = bm + r0;      if (ra0 > Mtot - 1) ra0 = Mtot - 1;
        int ra1 = bm + r0 + 16; if (ra1 > Mtot - 1) ra1 = Mtot - 1;
        gload_lds16(A + (size_t)ra0 * DIM + k0 + cc, As + wid * 1024);
        gload_lds16(A + (size_t)ra1 * DIM + k0 + cc, As + wid * 1024 + 512);
        int rb0 = bn + r0, rb1 = bn + r0 + 16;
        gload_lds16(Bw + (size_t)rb0 * DIM + k0 + cc, Bs + wid * 1024);
        gload_lds16(Bw + (size_t)rb1 * DIM + k0 + cc, Bs + wid * 1024 + 512);
        __syncthreads();

        bf16x8 af[4], bfr[4];
#pragma unroll
        for (int m = 0; m < 4; ++m)
            af[m] = *reinterpret_cast<const bf16x8*>(
                As + (wr * 64 + m * 16 + (lane & 15)) * 32 + (lane >> 4) * 8);
#pragma unroll
        for (int n = 0; n < 4; ++n)
            bfr[n] = *reinterpret_cast<const bf16x8*>(
                Bs + (wc * 64 + n * 16 + (lane & 15)) * 32 + (lane >> 4) * 8);
#pragma unroll
        for (int m = 0; m < 4; ++m)
#pragma unroll
            for (int n = 0; n < 4; ++n)
                acc[m][n] = __builtin_amdgcn_mfma_f32_16x16x32_bf16(
                    af[m], bfr[n], acc[m][n], 0, 0, 0);
        __syncthreads();
    }

    const int colb = bn + wc * 64 + (lane & 15);
    const int rowb = bm + wr * 64 + ((lane >> 4) << 2);
    const int which = bn >> 10;   // 0=Q 1=K 2=V (MODE 0)

#pragma unroll
    for (int m = 0; m < 4; ++m) {
#pragma unroll
        for (int n = 0; n < 4; ++n) {
            const int col = colb + n * 16;
            const int nn  = col & 1023;
            const int h   = nn >> 6;
            const int dh  = nn & 63;
#pragma unroll
            for (int qreg = 0; qreg < 4; ++qreg) {
                const int row = rowb + m * 16 + qreg;
                float val   = acc[m][n][qreg];
                float other = __shfl_xor(val, 1);
                if (row >= Mtot) continue;
                if (MODE == 1) {
                    outp[(size_t)row * DIM + col] = val;
                } else {
                    const int b = row >= SS;
                    const int s = row - b * SS;
                    if (which == 2) {
                        vb[(((size_t)b * NH + h) * SS + s) * DHD + dh] = f2bf(val);
                    } else {
                        if (s >= PFX) {
                            const int pos = s - PFX;
                            float cs = ropeC[pos * 32 + (dh >> 1)];
                            float sn = ropeS[pos * 32 + (dh >> 1)];
                            val = (dh & 1) ? (other * sn + val * cs)
                                           : (val * cs - other * sn);
                        }
                        if (which == 0) {
                            if (s >= PFX)
                                qb[(((size_t)b * NH + h) * LL + (s - PFX)) * DHD + dh] = f2bf(val);
                        } else {
                            kb[(((size_t)b * NH + h) * SS + s) * DHD + dh] = f2bf(val);
                        }
                    }
                }
            }
        }
    }
}

// ---------------------------------------------------------------------------
// MFMA flash attention. Block = 4 waves x 32 q-rows (TQ=128), TK=64.
// Swapped QK^T (S^T = K*Q^T) so each lane owns one q-column: softmax is
// in-lane + one xor-32 shuffle. P -> bf16 B-frags via cvt_pk_bf16_f32 +
// v_permlane32_swap_b32 (no LDS round-trip). PV as O^T = V^T * P^T.
// K LDS [key][d], V LDS [dh][key], both XOR-swizzled (G4: 128B rows).
// ---------------------------------------------------------------------------
__global__ __launch_bounds__(256, 3)
void attn_mfma(const u16* __restrict__ qb, const u16* __restrict__ kb,
               const u16* __restrict__ vb, u16* __restrict__ ctx)
{
    __shared__ u16 Ks[64 * 64] __attribute__((aligned(16)));
    __shared__ u16 Vt[64 * 64] __attribute__((aligned(16)));
    __shared__ u16 Ot[4][32 * 72] __attribute__((aligned(16)));

    const int tid  = threadIdx.x;
    const int lane = tid & 63;
    const int wv   = tid >> 6;
    const int h    = lane >> 5;       // half
    const int ql   = lane & 31;       // this lane's q (col) / row index

    const int bh   = blockIdx.y;
    const int b    = bh >> 4;
    const int head = bh & 15;
    int qt = blockIdx.x;
    if (b) qt = 15 - qt;              // pair heavy+light q-tiles
    const int q0  = qt * 128;
    const int q0w = q0 + 32 * wv;

    // Q B-frags (col=q=ql, k=16ks+8h+j), persistent
    const u16* qrow = qb + ((size_t)bh * LL + q0w + ql) * DHD;
    bf16x8 qf[4];
#pragma unroll
    for (int ks = 0; ks < 4; ++ks) {
        I4B8 t; t.i = *reinterpret_cast<const int4*>(qrow + ks * 16 + h * 8);
        qf[ks] = t.v;
    }

    f32x16 oa0 = (f32x16)(0.f), oa1 = (f32x16)(0.f);
    float m = -INFINITY, l = 0.f;

    const u16* kb0 = kb + (size_t)bh * SS * DHD;
    const u16* vb0 = vb + (size_t)bh * SS * DHD;

    const int ntiles   = (PFX + q0 + 128 + 63) / 64;
    const int wave_lim = PFX + q0w + 31;
    const int vp = tid & 31;          // V staging: key pair
    const int vo = tid >> 5;          // V staging: dh oct

    for (int kt = 0; kt < ntiles; ++kt) {
        const int j0 = kt * 64;

        // ---- stage K [key][d], swizzled ----
#pragma unroll
        for (int i = 0; i < 2; ++i) {
            int c = tid + i * 256;
            int key = c >> 3, o = c & 7;
            int jg = j0 + key; if (jg > SS - 1) jg = SS - 1;
            int4 kv = *reinterpret_cast<const int4*>(kb0 + (size_t)jg * DHD + o * 8);
            *reinterpret_cast<int4*>((char*)Ks + ((key * 128 + o * 16) ^ ((key & 7) << 4))) = kv;
        }
        // ---- stage V^T [dh][key], swizzled ----
        {
            int ja = j0 + 2 * vp;     if (ja > SS - 1) ja = SS - 1;
            int jb2 = j0 + 2 * vp + 1; if (jb2 > SS - 1) jb2 = SS - 1;
            int4 v0 = *reinterpret_cast<const int4*>(vb0 + (size_t)ja * DHD + vo * 8);
            int4 v1 = *reinterpret_cast<const int4*>(vb0 + (size_t)jb2 * DHD + vo * 8);
            const u16* pa = reinterpret_cast<const u16*>(&v0);
            const u16* pb = reinterpret_cast<const u16*>(&v1);
#pragma unroll
            for (int d = 0; d < 8; ++d) {
                u32 wpk = (u32)pa[d] | ((u32)pb[d] << 16);
                int dh = vo * 8 + d;
                *reinterpret_cast<u32*>((char*)Vt + ((dh * 128 + vp * 4) ^ ((d & 7) << 4))) = wpk;
            }
        }
        __syncthreads();

        if (j0 <= wave_lim) {
            // ---- S^T = K . Q^T ----
            f32x16 s0 = (f32x16)(0.f), s1 = (f32x16)(0.f);
#pragma unroll
            for (int ks = 0; ks < 4; ++ks) {
                I4B8 k0, k1;
                k0.i = *reinterpret_cast<const int4*>(
                    (const char*)Ks + (((ql) * 128 + ks * 32 + h * 16) ^ ((ql & 7) << 4)));
                k1.i = *reinterpret_cast<const int4*>(
                    (const char*)Ks + (((32 + ql) * 128 + ks * 32 + h * 16) ^ ((ql & 7) << 4)));
                s0 = __builtin_amdgcn_mfma_f32_32x32x16_bf16(k0.v, qf[ks], s0, 0, 0, 0);
                s1 = __builtin_amdgcn_mfma_f32_32x32x16_bf16(k1.v, qf[ks], s1, 0, 0, 0);
            }
            // ---- scale + causal mask ----
            float sv[32];
#pragma unroll
            for (int i = 0; i < 16; ++i) { sv[i] = s0[i] * 0.125f; sv[16 + i] = s1[i] * 0.125f; }
            if (j0 + 63 > PFX + q0w) {
                const int lim = PFX + q0w + ql - j0;
#pragma unroll
                for (int i = 0; i < 32; ++i) {
                    int koff = ((i >= 16) ? 32 : 0) + (i & 3) + 8 * ((i & 15) >> 2) + 4 * h;
                    if (koff > lim) sv[i] = -INFINITY;
                }
            }
            // ---- online softmax (per-lane scalar m,l) ----
            float mt = sv[0];
#pragma unroll
            for (int i = 1; i < 32; ++i) mt = fmaxf(mt, sv[i]);
            mt = fmaxf(mt, __shfl_xor(mt, 32));
            float mn = fmaxf(m, mt);
            float f = __expf(m - mn);
            m = mn;
            float ls = 0.f;
            u32 W0[8], W1[8];
#pragma unroll
            for (int i = 0; i < 8; ++i) {
                float pa = __expf(sv[2 * i] - m);
                float pb = __expf(sv[2 * i + 1] - m);
                ls += pa + pb;
                W0[i] = cvtpk(pa, pb);
            }
#pragma unroll
            for (int i = 0; i < 8; ++i) {
                float pa = __expf(sv[16 + 2 * i] - m);
                float pb = __expf(sv[16 + 2 * i + 1] - m);
                ls += pa + pb;
                W1[i] = cvtpk(pa, pb);
            }
            ls += __shfl_xor(ls, 32);
            l = l * f + ls;
#pragma unroll
            for (int i = 0; i < 16; ++i) { oa0[i] *= f; oa1[i] *= f; }

            // ---- PV: O^T += V^T . P^T ----
#pragma unroll
            for (int ks = 0; ks < 4; ++ks) {
                const int a4 = (ks & 1) * 4;
                u32 A0, A1, A2, A3;
                if (ks < 2) { A0 = W0[a4]; A1 = W0[a4 + 1]; A2 = W0[a4 + 2]; A3 = W0[a4 + 3]; }
                else        { A0 = W1[a4]; A1 = W1[a4 + 1]; A2 = W1[a4 + 2]; A3 = W1[a4 + 3]; }
                asm volatile("v_permlane32_swap_b32 %0, %1" : "+v"(A0), "+v"(A2));
                asm volatile("v_permlane32_swap_b32 %0, %1" : "+v"(A1), "+v"(A3));
                I4B8 pf; pf.i = make_int4((int)A0, (int)A1, (int)A2, (int)A3);
                I4B8 vf0, vf1;
                vf0.i = *reinterpret_cast<const int4*>(
                    (const char*)Vt + (((ql) * 128 + ks * 32 + h * 16) ^ ((ql & 7) << 4)));
                vf1.i = *reinterpret_cast<const int4*>(
                    (const char*)Vt + (((32 + ql) * 128 + ks * 32 + h * 16) ^ ((ql & 7) << 4)));
                oa0 = __builtin_amdgcn_mfma_f32_32x32x16_bf16(vf0.v, pf.v, oa0, 0, 0, 0);
                oa1 = __builtin_amdgcn_mfma_f32_32x32x16_bf16(vf1.v, pf.v, oa1, 0, 0, 0);
            }
        }
        __syncthreads();
    }

    // ---- epilogue: normalize, transpose via per-wave LDS, coalesced store ----
    const float inv = 1.f / l;
    u16* orow = &Ot[wv][ql * 72];
#pragma unroll
    for (int i = 0; i < 8; ++i) {
        u32 w0 = cvtpk(oa0[2 * i] * inv, oa0[2 * i + 1] * inv);
        u32 w1 = cvtpk(oa1[2 * i] * inv, oa1[2 * i + 1] * inv);
        int dh0 = ((2 * i) & 3) + 8 * ((2 * i) >> 2) + 4 * h;   // even
        *reinterpret_cast<u32*>(&orow[dh0]) = w0;
        *reinterpret_cast<u32*>(&orow[32 + dh0]) = w1;
    }
    const int rr = lane >> 1, hh = lane & 1;
    const u16* src = &Ot[wv][rr * 72 + hh * 32];
    u16* dst = ctx + ((size_t)(b * LL + q0 + 32 * wv + rr)) * DIM + head * DHD + hh * 32;
#pragma unroll
    for (int i = 0; i < 4; ++i) {     // FIX: was i<4/2 bug -> full 32 u16 per lane
        int4 t = *reinterpret_cast<const int4*>(src + i * 8);
        *reinterpret_cast<int4*>(dst + i * 8) = t;
    }
}

// ---------------------------------------------------------------------------
extern "C" void kernel_launch(void* const* d_in, const int* in_sizes, int n_in,
                              void* d_out, int out_size, void* d_ws, size_t ws_size,
                              hipStream_t stream)
{
    const float* x  = (const float*)d_in[0];
    const float* pe = (const float*)d_in[1];
    const float* me = (const float*)d_in[2];
    const float* Wq = (const float*)d_in[3];
    const float* Wk = (const float*)d_in[4];
    const float* Wv = (const float*)d_in[5];
    const float* Wo = (const float*)d_in[6];
    float* out = (float*)d_out;

    u16* xbf  = (u16*)d_ws;                           // 4256x1024
    u16* wqkv = xbf + (size_t)MQKV * DIM;             // 3072x1024
    u16* wobf = wqkv + (size_t)NQKV * DIM;            // 1024x1024
    float* ropeC = (float*)(wobf + (size_t)DIM * DIM);
    float* ropeS = ropeC + LL * 32;
    u16* qbf = (u16*)(ropeS + LL * 32);               // B*H*L*DH
    u16* kbf = qbf + (size_t)BB * NH * LL * DHD;      // B*H*S*DH
    u16* vbf = kbf + (size_t)BB * NH * SS * DHD;      // B*H*S*DH
    u16* ctx = vbf + (size_t)BB * NH * SS * DHD;      // B*L*DIM

    hipLaunchKernelGGL(prep_kernel, dim3(2048), dim3(256), 0, stream,
                       x, pe, me, Wq, Wk, Wv, Wo, xbf, wqkv, wobf, ropeC, ropeS);
    hipLaunchKernelGGL((mfma_gemm<0>), dim3((MQKV + 127) / 128, NQKV / 128), dim3(256), 0, stream,
                       xbf, wqkv, ropeC, ropeS, qbf, kbf, vbf, nullptr);
    hipLaunchKernelGGL(attn_mfma, dim3(16, BB * NH), dim3(256), 0, stream,
                       qbf, kbf, vbf, ctx);
    hipLaunchKernelGGL((mfma_gemm<1>), dim3(MOUT / 128, DIM / 128), dim3(256), 0, stream,
                       ctx, wobf, nullptr, nullptr, nullptr, nullptr, nullptr, out);
}

// Round 6
// 153.120 us; speedup vs baseline: 30.7814x; 1.1497x over previous
//
#include <hip/hip_runtime.h>
#include <math.h>

#define BB    2
#define LL    2048
#define DIM   1024
#define NH    16
#define DHD   64
#define NPER  16
#define NMEM  64
#define PFX   80      // NPER + NMEM
#define SS    2128    // PFX + LL
#define MQKV  (BB*SS) // 4256
#define NQKV  3072
#define MOUT  (BB*LL) // 4096

typedef __attribute__((ext_vector_type(4)))  float f32x4;
typedef __attribute__((ext_vector_type(16))) float f32x16;
typedef __attribute__((ext_vector_type(8)))  short bf16x8;
typedef unsigned short u16;
typedef unsigned int   u32;

union I4B8 { int4 i; bf16x8 v; };

__device__ __forceinline__ u16 f2bf(float x) {
    union { float f; u32 u; } v; v.f = x;
    return (u16)((v.u + 0x7fffu + ((v.u >> 16) & 1u)) >> 16);
}
__device__ __forceinline__ u32 cvtpk(float lo, float hi) {
    u32 r; asm("v_cvt_pk_bf16_f32 %0, %1, %2" : "=v"(r) : "v"(lo), "v"(hi));
    return r;
}
__device__ __forceinline__ void gload_lds16(const void* g, void* l) {
    __builtin_amdgcn_global_load_lds(
        (__attribute__((address_space(1))) void*)(g),
        (__attribute__((address_space(3))) void*)(l), 16, 0, 0);
}

// ---------------------------------------------------------------------------
// Prep: fp32 -> bf16 conversions + RoPE tables
// ---------------------------------------------------------------------------
__global__ __launch_bounds__(256)
void prep_kernel(const float* __restrict__ x,  const float* __restrict__ pe,
                 const float* __restrict__ me, const float* __restrict__ Wq,
                 const float* __restrict__ Wk, const float* __restrict__ Wv,
                 const float* __restrict__ Wo,
                 u16* __restrict__ xbf, u16* __restrict__ wqkv,
                 u16* __restrict__ wobf,
                 float* __restrict__ ropeC, float* __restrict__ ropeS)
{
    const int nthr = gridDim.x * blockDim.x;
    const int t0   = blockIdx.x * blockDim.x + threadIdx.x;

    for (int g = t0; g < MQKV * (DIM / 4); g += nthr) {
        int d4  = g & 255;
        int row = g >> 8;
        int b   = row >= SS;
        int s   = row - b * SS;
        const float* src;
        if (s < NPER)     src = pe + ((size_t)(b * NPER + s)) * DIM;
        else if (s < PFX) src = me + ((size_t)(b * NMEM + (s - NPER))) * DIM;
        else              src = x  + ((size_t)(b * LL   + (s - PFX)))  * DIM;
        float4 v = *reinterpret_cast<const float4*>(src + d4 * 4);
        ushort4 o; o.x = f2bf(v.x); o.y = f2bf(v.y); o.z = f2bf(v.z); o.w = f2bf(v.w);
        *reinterpret_cast<ushort4*>(xbf + (size_t)g * 4) = o;
    }
    for (int g = t0; g < NQKV * (DIM / 4); g += nthr) {
        int row = g >> 8;
        const float* src = (row < 1024) ? (Wq + (size_t)row * DIM)
                         : (row < 2048) ? (Wk + (size_t)(row - 1024) * DIM)
                         :                (Wv + (size_t)(row - 2048) * DIM);
        float4 v = *reinterpret_cast<const float4*>(src + (g & 255) * 4);
        ushort4 o; o.x = f2bf(v.x); o.y = f2bf(v.y); o.z = f2bf(v.z); o.w = f2bf(v.w);
        *reinterpret_cast<ushort4*>(wqkv + (size_t)g * 4) = o;
    }
    for (int g = t0; g < DIM * (DIM / 4); g += nthr) {
        float4 v = *reinterpret_cast<const float4*>(Wo + (size_t)g * 4);
        ushort4 o; o.x = f2bf(v.x); o.y = f2bf(v.y); o.z = f2bf(v.z); o.w = f2bf(v.w);
        *reinterpret_cast<ushort4*>(wobf + (size_t)g * 4) = o;
    }
    for (int i = t0; i < LL * 32; i += nthr) {
        int pos = i >> 5, fi = i & 31;
        float ang = (float)pos * exp2f(-(float)fi * 0.41524101186092029f);
        ropeC[i] = cosf(ang);
        ropeS[i] = sinf(ang);
    }
}

// ---------------------------------------------------------------------------
// bf16 MFMA GEMM, 128x128 tile, BK=32, 4 waves (2x2 quadrants).
// OPERAND-SWAPPED: A-operand = weight frag (D-row = output col), B-operand =
// x frag (D-col = x row). Each lane's 4 acc regs = 4 CONSECUTIVE output cols
// -> in-lane RoPE pairs, ushort4/float4 vector stores.
// MODE 0: A=xfull, W=Wqkv -> RoPE epilogue, bf16 q/k/v scatter.
// MODE 1: A=ctx bf16, W=Wo -> fp32 out, float4 stores.
// ---------------------------------------------------------------------------
template <int MODE>
__global__ __launch_bounds__(256)
void mfma_gemm(const u16* __restrict__ A, const u16* __restrict__ Bw,
               const float* __restrict__ ropeC, const float* __restrict__ ropeS,
               u16* __restrict__ qb, u16* __restrict__ kb,
               u16* __restrict__ vb, float* __restrict__ outp)
{
    __shared__ short As[128 * 32] __attribute__((aligned(16)));
    __shared__ short Bs[128 * 32] __attribute__((aligned(16)));

    const int tid  = threadIdx.x;
    const int lane = tid & 63;
    const int wid  = tid >> 6;
    const int wr   = wid >> 1, wc = wid & 1;
    const int bm   = blockIdx.x * 128;   // x-row tile base
    const int bn   = blockIdx.y * 128;   // weight-row (output col) tile base
    const int Mtot = (MODE == 0) ? MQKV : MOUT;

    f32x4 acc[4][4];   // [m: col group][n: row group]
#pragma unroll
    for (int m = 0; m < 4; ++m)
#pragma unroll
        for (int n = 0; n < 4; ++n) acc[m][n] = (f32x4)(0.f);

    const int r0 = wid * 32 + (lane >> 2);
    const int cc = (lane & 3) * 8;

    for (int k0 = 0; k0 < DIM; k0 += 32) {
        int ra0 = bm + r0;      if (ra0 > Mtot - 1) ra0 = Mtot - 1;
        int ra1 = bm + r0 + 16; if (ra1 > Mtot - 1) ra1 = Mtot - 1;
        gload_lds16(A + (size_t)ra0 * DIM + k0 + cc, As + wid * 1024);
        gload_lds16(A + (size_t)ra1 * DIM + k0 + cc, As + wid * 1024 + 512);
        int rb0 = bn + r0, rb1 = bn + r0 + 16;
        gload_lds16(Bw + (size_t)rb0 * DIM + k0 + cc, Bs + wid * 1024);
        gload_lds16(Bw + (size_t)rb1 * DIM + k0 + cc, Bs + wid * 1024 + 512);
        __syncthreads();

        bf16x8 wf[4], xf[4];
#pragma unroll
        for (int m = 0; m < 4; ++m)
            wf[m] = *reinterpret_cast<const bf16x8*>(
                Bs + (wr * 64 + m * 16 + (lane & 15)) * 32 + (lane >> 4) * 8);
#pragma unroll
        for (int n = 0; n < 4; ++n)
            xf[n] = *reinterpret_cast<const bf16x8*>(
                As + (wc * 64 + n * 16 + (lane & 15)) * 32 + (lane >> 4) * 8);
#pragma unroll
        for (int m = 0; m < 4; ++m)
#pragma unroll
            for (int n = 0; n < 4; ++n)
                acc[m][n] = __builtin_amdgcn_mfma_f32_16x16x32_bf16(
                    wf[m], xf[n], acc[m][n], 0, 0, 0);
        __syncthreads();
    }

    // epilogue: col c0 = bn + wr*64 + m*16 + (lane>>4)*4 (+qreg), 4 consecutive
    //           row    = bm + wc*64 + n*16 + (lane&15)
    const int cbase = bn + wr * 64 + ((lane >> 4) << 2);
    const int rbase = bm + wc * 64 + (lane & 15);
    const int which = bn >> 10;   // block-uniform: 0=Q 1=K 2=V (MODE 0)

#pragma unroll
    for (int n = 0; n < 4; ++n) {
        const int row = rbase + n * 16;
        if (row >= Mtot) continue;
        const int b = row >= SS;
        const int s = row - b * SS;
#pragma unroll
        for (int m = 0; m < 4; ++m) {
            const int c0 = cbase + m * 16;
            float v0 = acc[m][n][0], v1 = acc[m][n][1];
            float v2 = acc[m][n][2], v3 = acc[m][n][3];
            if (MODE == 1) {
                *reinterpret_cast<float4*>(&outp[(size_t)row * DIM + c0]) =
                    make_float4(v0, v1, v2, v3);
            } else {
                const int nn = c0 & 1023;
                const int h  = nn >> 6;
                const int dh = nn & 63;
                if (which != 2 && s >= PFX) {
                    const int pos = s - PFX;
                    float2 cs = *reinterpret_cast<const float2*>(ropeC + pos * 32 + (dh >> 1));
                    float2 sn = *reinterpret_cast<const float2*>(ropeS + pos * 32 + (dh >> 1));
                    float t0 = v0 * cs.x - v1 * sn.x;
                    v1 = v0 * sn.x + v1 * cs.x; v0 = t0;
                    float t2 = v2 * cs.y - v3 * sn.y;
                    v3 = v2 * sn.y + v3 * cs.y; v2 = t2;
                }
                ushort4 o;
                o.x = f2bf(v0); o.y = f2bf(v1); o.z = f2bf(v2); o.w = f2bf(v3);
                if (which == 0) {
                    if (s >= PFX)
                        *reinterpret_cast<ushort4*>(
                            &qb[(((size_t)b * NH + h) * LL + (s - PFX)) * DHD + dh]) = o;
                } else if (which == 1) {
                    *reinterpret_cast<ushort4*>(
                        &kb[(((size_t)b * NH + h) * SS + s) * DHD + dh]) = o;
                } else {
                    *reinterpret_cast<ushort4*>(
                        &vb[(((size_t)b * NH + h) * SS + s) * DHD + dh]) = o;
                }
            }
        }
    }
}

// ---------------------------------------------------------------------------
// MFMA flash attention (swapped QK^T + in-register softmax), with T14
// async-stage (prefetch next K/V tile into regs before compute) and T5
// setprio around MFMA clusters.
// ---------------------------------------------------------------------------
__device__ __forceinline__ void attn_load_tile(
    const u16* __restrict__ kb0, const u16* __restrict__ vb0,
    int j0, int tid, int vp, int vo,
    int4& k0r, int4& k1r, int4& v0r, int4& v1r)
{
    int key0 = tid >> 3,        o0 = tid & 7;
    int c1   = tid + 256;
    int key1 = c1 >> 3,         o1 = c1 & 7;
    int jg0 = j0 + key0; if (jg0 > SS - 1) jg0 = SS - 1;
    int jg1 = j0 + key1; if (jg1 > SS - 1) jg1 = SS - 1;
    k0r = *reinterpret_cast<const int4*>(kb0 + (size_t)jg0 * DHD + o0 * 8);
    k1r = *reinterpret_cast<const int4*>(kb0 + (size_t)jg1 * DHD + o1 * 8);
    int ja  = j0 + 2 * vp;     if (ja  > SS - 1) ja  = SS - 1;
    int jb2 = j0 + 2 * vp + 1; if (jb2 > SS - 1) jb2 = SS - 1;
    v0r = *reinterpret_cast<const int4*>(vb0 + (size_t)ja  * DHD + vo * 8);
    v1r = *reinterpret_cast<const int4*>(vb0 + (size_t)jb2 * DHD + vo * 8);
}

__global__ __launch_bounds__(256, 2)
void attn_mfma(const u16* __restrict__ qb, const u16* __restrict__ kb,
               const u16* __restrict__ vb, u16* __restrict__ ctx)
{
    __shared__ u16 Ks[64 * 64] __attribute__((aligned(16)));
    __shared__ u16 Vt[64 * 64] __attribute__((aligned(16)));
    __shared__ u16 Ot[4][32 * 72] __attribute__((aligned(16)));

    const int tid  = threadIdx.x;
    const int lane = tid & 63;
    const int wv   = tid >> 6;
    const int h    = lane >> 5;       // half
    const int ql   = lane & 31;       // this lane's q (col) / row index

    const int bh   = blockIdx.y;
    const int b    = bh >> 4;
    const int head = bh & 15;
    int qt = blockIdx.x;
    if (b) qt = 15 - qt;              // pair heavy+light q-tiles
    const int q0  = qt * 128;
    const int q0w = q0 + 32 * wv;

    const u16* qrow = qb + ((size_t)bh * LL + q0w + ql) * DHD;
    bf16x8 qf[4];
#pragma unroll
    for (int ks = 0; ks < 4; ++ks) {
        I4B8 t; t.i = *reinterpret_cast<const int4*>(qrow + ks * 16 + h * 8);
        qf[ks] = t.v;
    }

    f32x16 oa0 = (f32x16)(0.f), oa1 = (f32x16)(0.f);
    float m = -INFINITY, l = 0.f;

    const u16* kb0 = kb + (size_t)bh * SS * DHD;
    const u16* vb0 = vb + (size_t)bh * SS * DHD;

    const int ntiles   = (PFX + q0 + 128 + 63) / 64;
    const int wave_lim = PFX + q0w + 31;
    const int vp = tid & 31;          // V staging: key pair
    const int vo = tid >> 5;          // V staging: dh oct

    int4 rk0, rk1, rv0, rv1;
    attn_load_tile(kb0, vb0, 0, tid, vp, vo, rk0, rk1, rv0, rv1);

    for (int kt = 0; kt < ntiles; ++kt) {
        const int j0 = kt * 64;

        // ---- write prefetched regs -> LDS (swizzled) ----
        {
            int key0 = tid >> 3, o0 = tid & 7;
            int c1 = tid + 256;
            int key1 = c1 >> 3, o1 = c1 & 7;
            *reinterpret_cast<int4*>((char*)Ks + ((key0 * 128 + o0 * 16) ^ ((key0 & 7) << 4))) = rk0;
            *reinterpret_cast<int4*>((char*)Ks + ((key1 * 128 + o1 * 16) ^ ((key1 & 7) << 4))) = rk1;
            const u16* pa = reinterpret_cast<const u16*>(&rv0);
            const u16* pb = reinterpret_cast<const u16*>(&rv1);
#pragma unroll
            for (int d = 0; d < 8; ++d) {
                u32 wpk = (u32)pa[d] | ((u32)pb[d] << 16);
                int dh = vo * 8 + d;
                *reinterpret_cast<u32*>((char*)Vt + ((dh * 128 + vp * 4) ^ ((d & 7) << 4))) = wpk;
            }
        }
        __syncthreads();

        // ---- issue next tile's global loads (latency hides under compute) ----
        int4 nk0, nk1, nv0, nv1;
        attn_load_tile(kb0, vb0, j0 + 64, tid, vp, vo, nk0, nk1, nv0, nv1);

        if (j0 <= wave_lim) {
            // ---- S^T = K . Q^T ----
            f32x16 s0 = (f32x16)(0.f), s1 = (f32x16)(0.f);
            __builtin_amdgcn_s_setprio(1);
#pragma unroll
            for (int ks = 0; ks < 4; ++ks) {
                I4B8 k0, k1;
                k0.i = *reinterpret_cast<const int4*>(
                    (const char*)Ks + (((ql) * 128 + ks * 32 + h * 16) ^ ((ql & 7) << 4)));
                k1.i = *reinterpret_cast<const int4*>(
                    (const char*)Ks + (((32 + ql) * 128 + ks * 32 + h * 16) ^ ((ql & 7) << 4)));
                s0 = __builtin_amdgcn_mfma_f32_32x32x16_bf16(k0.v, qf[ks], s0, 0, 0, 0);
                s1 = __builtin_amdgcn_mfma_f32_32x32x16_bf16(k1.v, qf[ks], s1, 0, 0, 0);
            }
            __builtin_amdgcn_s_setprio(0);
            // ---- scale + causal mask ----
            float sv[32];
#pragma unroll
            for (int i = 0; i < 16; ++i) { sv[i] = s0[i] * 0.125f; sv[16 + i] = s1[i] * 0.125f; }
            if (j0 + 63 > PFX + q0w) {
                const int lim = PFX + q0w + ql - j0;
#pragma unroll
                for (int i = 0; i < 32; ++i) {
                    int koff = ((i >= 16) ? 32 : 0) + (i & 3) + 8 * ((i & 15) >> 2) + 4 * h;
                    if (koff > lim) sv[i] = -INFINITY;
                }
            }
            // ---- online softmax (per-lane scalar m,l) ----
            float mt = sv[0];
#pragma unroll
            for (int i = 1; i < 32; ++i) mt = fmaxf(mt, sv[i]);
            mt = fmaxf(mt, __shfl_xor(mt, 32));
            float mn = fmaxf(m, mt);
            float f = __expf(m - mn);
            m = mn;
            float ls = 0.f;
            u32 W0[8], W1[8];
#pragma unroll
            for (int i = 0; i < 8; ++i) {
                float pa = __expf(sv[2 * i] - m);
                float pb = __expf(sv[2 * i + 1] - m);
                ls += pa + pb;
                W0[i] = cvtpk(pa, pb);
            }
#pragma unroll
            for (int i = 0; i < 8; ++i) {
                float pa = __expf(sv[16 + 2 * i] - m);
                float pb = __expf(sv[16 + 2 * i + 1] - m);
                ls += pa + pb;
                W1[i] = cvtpk(pa, pb);
            }
            ls += __shfl_xor(ls, 32);
            l = l * f + ls;
#pragma unroll
            for (int i = 0; i < 16; ++i) { oa0[i] *= f; oa1[i] *= f; }

            // ---- PV: O^T += V^T . P^T ----
            __builtin_amdgcn_s_setprio(1);
#pragma unroll
            for (int ks = 0; ks < 4; ++ks) {
                const int a4 = (ks & 1) * 4;
                u32 A0, A1, A2, A3;
                if (ks < 2) { A0 = W0[a4]; A1 = W0[a4 + 1]; A2 = W0[a4 + 2]; A3 = W0[a4 + 3]; }
                else        { A0 = W1[a4]; A1 = W1[a4 + 1]; A2 = W1[a4 + 2]; A3 = W1[a4 + 3]; }
                asm volatile("v_permlane32_swap_b32 %0, %1" : "+v"(A0), "+v"(A2));
                asm volatile("v_permlane32_swap_b32 %0, %1" : "+v"(A1), "+v"(A3));
                I4B8 pf; pf.i = make_int4((int)A0, (int)A1, (int)A2, (int)A3);
                I4B8 vf0, vf1;
                vf0.i = *reinterpret_cast<const int4*>(
                    (const char*)Vt + (((ql) * 128 + ks * 32 + h * 16) ^ ((ql & 7) << 4)));
                vf1.i = *reinterpret_cast<const int4*>(
                    (const char*)Vt + (((32 + ql) * 128 + ks * 32 + h * 16) ^ ((ql & 7) << 4)));
                oa0 = __builtin_amdgcn_mfma_f32_32x32x16_bf16(vf0.v, pf.v, oa0, 0, 0, 0);
                oa1 = __builtin_amdgcn_mfma_f32_32x32x16_bf16(vf1.v, pf.v, oa1, 0, 0, 0);
            }
            __builtin_amdgcn_s_setprio(0);
        }
        __syncthreads();
        rk0 = nk0; rk1 = nk1; rv0 = nv0; rv1 = nv1;
    }

    // ---- epilogue: normalize, transpose via per-wave LDS, coalesced store ----
    const float inv = 1.f / l;
    u16* orow = &Ot[wv][ql * 72];
#pragma unroll
    for (int i = 0; i < 8; ++i) {
        u32 w0 = cvtpk(oa0[2 * i] * inv, oa0[2 * i + 1] * inv);
        u32 w1 = cvtpk(oa1[2 * i] * inv, oa1[2 * i + 1] * inv);
        int dh0 = ((2 * i) & 3) + 8 * ((2 * i) >> 2) + 4 * h;   // even
        *reinterpret_cast<u32*>(&orow[dh0]) = w0;
        *reinterpret_cast<u32*>(&orow[32 + dh0]) = w1;
    }
    const int rr = lane >> 1, hh = lane & 1;
    const u16* src = &Ot[wv][rr * 72 + hh * 32];
    u16* dst = ctx + ((size_t)(b * LL + q0 + 32 * wv + rr)) * DIM + head * DHD + hh * 32;
#pragma unroll
    for (int i = 0; i < 4; ++i) {
        int4 t = *reinterpret_cast<const int4*>(src + i * 8);
        *reinterpret_cast<int4*>(dst + i * 8) = t;
    }
}

// ---------------------------------------------------------------------------
extern "C" void kernel_launch(void* const* d_in, const int* in_sizes, int n_in,
                              void* d_out, int out_size, void* d_ws, size_t ws_size,
                              hipStream_t stream)
{
    const float* x  = (const float*)d_in[0];
    const float* pe = (const float*)d_in[1];
    const float* me = (const float*)d_in[2];
    const float* Wq = (const float*)d_in[3];
    const float* Wk = (const float*)d_in[4];
    const float* Wv = (const float*)d_in[5];
    const float* Wo = (const float*)d_in[6];
    float* out = (float*)d_out;

    u16* xbf  = (u16*)d_ws;                           // 4256x1024
    u16* wqkv = xbf + (size_t)MQKV * DIM;             // 3072x1024
    u16* wobf = wqkv + (size_t)NQKV * DIM;            // 1024x1024
    float* ropeC = (float*)(wobf + (size_t)DIM * DIM);
    float* ropeS = ropeC + LL * 32;
    u16* qbf = (u16*)(ropeS + LL * 32);               // B*H*L*DH
    u16* kbf = qbf + (size_t)BB * NH * LL * DHD;      // B*H*S*DH
    u16* vbf = kbf + (size_t)BB * NH * SS * DHD;      // B*H*S*DH
    u16* ctx = vbf + (size_t)BB * NH * SS * DHD;      // B*L*DIM

    hipLaunchKernelGGL(prep_kernel, dim3(2048), dim3(256), 0, stream,
                       x, pe, me, Wq, Wk, Wv, Wo, xbf, wqkv, wobf, ropeC, ropeS);
    hipLaunchKernelGGL((mfma_gemm<0>), dim3((MQKV + 127) / 128, NQKV / 128), dim3(256), 0, stream,
                       xbf, wqkv, ropeC, ropeS, qbf, kbf, vbf, nullptr);
    hipLaunchKernelGGL(attn_mfma, dim3(16, BB * NH), dim3(256), 0, stream,
                       qbf, kbf, vbf, ctx);
    hipLaunchKernelGGL((mfma_gemm<1>), dim3(MOUT / 128, DIM / 128), dim3(256), 0, stream,
                       ctx, wobf, nullptr, nullptr, nullptr, nullptr, nullptr, out);
}

// Round 7
// 151.791 us; speedup vs baseline: 31.0510x; 1.0088x over previous
//
#include <hip/hip_runtime.h>
#include <math.h>

#define BB    2
#define LL    2048
#define DIM   1024
#define NH    16
#define DHD   64
#define NPER  16
#define NMEM  64
#define PFX   80      // NPER + NMEM
#define SS    2128    // PFX + LL
#define MQKV  (BB*SS) // 4256
#define NQKV  3072
#define MOUT  (BB*LL) // 4096

typedef __attribute__((ext_vector_type(4)))  float f32x4;
typedef __attribute__((ext_vector_type(16))) float f32x16;
typedef __attribute__((ext_vector_type(8)))  short bf16x8;
typedef unsigned short u16;
typedef unsigned int   u32;

union I4B8 { int4 i; bf16x8 v; };

__device__ __forceinline__ u16 f2bf(float x) {
    union { float f; u32 u; } v; v.f = x;
    return (u16)((v.u + 0x7fffu + ((v.u >> 16) & 1u)) >> 16);
}
__device__ __forceinline__ u32 cvtpk(float lo, float hi) {
    u32 r; asm("v_cvt_pk_bf16_f32 %0, %1, %2" : "=v"(r) : "v"(lo), "v"(hi));
    return r;
}
__device__ __forceinline__ void gload_lds16(const void* g, void* l) {
    __builtin_amdgcn_global_load_lds(
        (__attribute__((address_space(1))) void*)(g),
        (__attribute__((address_space(3))) void*)(l), 16, 0, 0);
}

#define BARRIER()  asm volatile("s_barrier" ::: "memory")
#define VMCNT8()   asm volatile("s_waitcnt vmcnt(8)" ::: "memory")

// ---------------------------------------------------------------------------
// Prep: fp32 -> bf16 conversions + RoPE tables
// ---------------------------------------------------------------------------
__global__ __launch_bounds__(256)
void prep_kernel(const float* __restrict__ x,  const float* __restrict__ pe,
                 const float* __restrict__ me, const float* __restrict__ Wq,
                 const float* __restrict__ Wk, const float* __restrict__ Wv,
                 const float* __restrict__ Wo,
                 u16* __restrict__ xbf, u16* __restrict__ wqkv,
                 u16* __restrict__ wobf,
                 float* __restrict__ ropeC, float* __restrict__ ropeS)
{
    const int nthr = gridDim.x * blockDim.x;
    const int t0   = blockIdx.x * blockDim.x + threadIdx.x;

    for (int g = t0; g < MQKV * (DIM / 4); g += nthr) {
        int d4  = g & 255;
        int row = g >> 8;
        int b   = row >= SS;
        int s   = row - b * SS;
        const float* src;
        if (s < NPER)     src = pe + ((size_t)(b * NPER + s)) * DIM;
        else if (s < PFX) src = me + ((size_t)(b * NMEM + (s - NPER))) * DIM;
        else              src = x  + ((size_t)(b * LL   + (s - PFX)))  * DIM;
        float4 v = *reinterpret_cast<const float4*>(src + d4 * 4);
        ushort4 o; o.x = f2bf(v.x); o.y = f2bf(v.y); o.z = f2bf(v.z); o.w = f2bf(v.w);
        *reinterpret_cast<ushort4*>(xbf + (size_t)g * 4) = o;
    }
    for (int g = t0; g < NQKV * (DIM / 4); g += nthr) {
        int row = g >> 8;
        const float* src = (row < 1024) ? (Wq + (size_t)row * DIM)
                         : (row < 2048) ? (Wk + (size_t)(row - 1024) * DIM)
                         :                (Wv + (size_t)(row - 2048) * DIM);
        float4 v = *reinterpret_cast<const float4*>(src + (g & 255) * 4);
        ushort4 o; o.x = f2bf(v.x); o.y = f2bf(v.y); o.z = f2bf(v.z); o.w = f2bf(v.w);
        *reinterpret_cast<ushort4*>(wqkv + (size_t)g * 4) = o;
    }
    for (int g = t0; g < DIM * (DIM / 4); g += nthr) {
        float4 v = *reinterpret_cast<const float4*>(Wo + (size_t)g * 4);
        ushort4 o; o.x = f2bf(v.x); o.y = f2bf(v.y); o.z = f2bf(v.z); o.w = f2bf(v.w);
        *reinterpret_cast<ushort4*>(wobf + (size_t)g * 4) = o;
    }
    for (int i = t0; i < LL * 32; i += nthr) {
        int pos = i >> 5, fi = i & 31;
        float ang = (float)pos * exp2f(-(float)fi * 0.41524101186092029f);
        ropeC[i] = cosf(ang);
        ropeS[i] = sinf(ang);
    }
}

// ---------------------------------------------------------------------------
// 8-phase 256x256 QKV GEMM (T2+T3+T4+T5). BK=64, 8 waves (2M x 4N),
// per-wave C = 128 x-rows x 64 w-cols. Double-buffered 128 KiB LDS.
// Swizzle: byte ^= (row&7)<<4, applied via pre-swizzled global source
// (linear gload_lds dest) + swizzled ds_read.  Counted vmcnt(8) at
// phases 4/8 only; raw s_barrier (no vmcnt(0) drain in main loop).
// Race-freedom: W-LDS reads of a tile complete by barrier2-of-phase2,
// X-LDS reads by barrier2-of-phase3  =>  stage W(t+2) in phase 3,
// X(t+2) in phase 4.
// ---------------------------------------------------------------------------
__device__ __forceinline__ void stage_half8(const u16* __restrict__ src, int grow0,
                                            int rmax, int k0, short* ldsbase, int tid)
{
#pragma unroll
    for (int rr = 0; rr < 2; ++rr) {
        int t   = tid + rr * 512;
        int row = t >> 3;           // 0..127 within half
        int c   = t & 7;            // 16B chunk
        int g = grow0 + row; if (g > rmax) g = rmax;
        gload_lds16(src + (size_t)g * DIM + k0 + ((c ^ (row & 7)) << 3),
                    ldsbase + (tid >> 6) * 512 + rr * 4096);
    }
}

__device__ __forceinline__ bf16x8 ldsfrag(const short* hb, int row, int kbyte)
{
    int byte = (row * 128 + kbyte) ^ ((row & 7) << 4);
    I4B8 t;
    t.i = *reinterpret_cast<const int4*>(reinterpret_cast<const char*>(hb) + byte);
    return t.v;
}

__global__ __launch_bounds__(512, 2)
void qkv_gemm8(const u16* __restrict__ X, const u16* __restrict__ Wq3,
               const float* __restrict__ ropeC, const float* __restrict__ ropeS,
               u16* __restrict__ qb, u16* __restrict__ kb, u16* __restrict__ vb)
{
    __shared__ short Xs[2][16384] __attribute__((aligned(16)));
    __shared__ short Ws[2][16384] __attribute__((aligned(16)));

    const int tid  = threadIdx.x;
    const int lane = tid & 63;
    const int wid  = tid >> 6;      // 0..7
    const int wm   = wid >> 2;      // 0..1 : x-row half (128 rows)
    const int wn   = wid & 3;       // 0..3 : w-col quarter (64 cols)
    const int bm   = blockIdx.x * 256;
    const int bn   = blockIdx.y * 256;

    f32x4 acc[8][4];
#pragma unroll
    for (int r = 0; r < 8; ++r)
#pragma unroll
        for (int c = 0; c < 4; ++c) acc[r][c] = (f32x4)(0.f);

    // ---- prologue: stage tiles 0 (buf0) and 1 (buf1): 16 loads/thread ----
    stage_half8(X,   bm,       MQKV - 1, 0,  &Xs[0][0],    tid);
    stage_half8(X,   bm + 128, MQKV - 1, 0,  &Xs[0][8192], tid);
    stage_half8(Wq3, bn,       NQKV - 1, 0,  &Ws[0][0],    tid);
    stage_half8(Wq3, bn + 128, NQKV - 1, 0,  &Ws[0][8192], tid);
    stage_half8(X,   bm,       MQKV - 1, 64, &Xs[1][0],    tid);
    stage_half8(X,   bm + 128, MQKV - 1, 64, &Xs[1][8192], tid);
    stage_half8(Wq3, bn,       NQKV - 1, 64, &Ws[1][0],    tid);
    stage_half8(Wq3, bn + 128, NQKV - 1, 64, &Ws[1][8192], tid);
    VMCNT8();       // tile 0 landed (tile 1's 8 loads may remain in flight)
    BARRIER();

    const int frow = lane & 15;
    const int fkb  = (lane >> 4) * 16;     // frag k byte offset
    const int wrow = (wn & 1) * 64;        // w-row base within W half
    const short* XhA[2] = { &Xs[0][0] + wm * 8192,        &Xs[1][0] + wm * 8192 };
    const short* WhA[2] = { &Ws[0][0] + (wn >> 1) * 8192, &Ws[1][0] + (wn >> 1) * 8192 };

    for (int it = 0; it < 8; ++it) {
        int ksA = it * 128 + 128; if (ksA >= 1024) ksA = 0;    // dummy restage, harmless
        int ksB = it * 128 + 192; if (ksB >= 1024) ksB = 64;
#pragma unroll
        for (int sub = 0; sub < 2; ++sub) {
            const short* Xh = XhA[sub];
            const short* Wh = WhA[sub];
            const int kst = sub ? ksB : ksA;
            short* XsN = &Xs[sub][0];
            short* WsN = &Ws[sub][0];
            bf16x8 xfA[4][2], xfB[4][2], wfA[2][2], wfB[2][2];

            // ---- phase 1: read xr0-3 + wc0-1; MFMA (xr0-3 x wc0-1) ----
#pragma unroll
            for (int r = 0; r < 4; ++r)
#pragma unroll
                for (int ks = 0; ks < 2; ++ks)
                    xfA[r][ks] = ldsfrag(Xh, r * 16 + frow, ks * 64 + fkb);
#pragma unroll
            for (int c = 0; c < 2; ++c)
#pragma unroll
                for (int ks = 0; ks < 2; ++ks)
                    wfA[c][ks] = ldsfrag(Wh, wrow + c * 16 + frow, ks * 64 + fkb);
            BARRIER();
            __builtin_amdgcn_s_setprio(1);
#pragma unroll
            for (int r = 0; r < 4; ++r)
#pragma unroll
                for (int c = 0; c < 2; ++c)
#pragma unroll
                    for (int ks = 0; ks < 2; ++ks)
                        acc[r][c] = __builtin_amdgcn_mfma_f32_16x16x32_bf16(
                            wfA[c][ks], xfA[r][ks], acc[r][c], 0, 0, 0);
            __builtin_amdgcn_s_setprio(0);
            BARRIER();

            // ---- phase 2: read wc2-3; MFMA (xr0-3 x wc2-3) ----
#pragma unroll
            for (int c = 0; c < 2; ++c)
#pragma unroll
                for (int ks = 0; ks < 2; ++ks)
                    wfB[c][ks] = ldsfrag(Wh, wrow + 32 + c * 16 + frow, ks * 64 + fkb);
            BARRIER();
            __builtin_amdgcn_s_setprio(1);
#pragma unroll
            for (int r = 0; r < 4; ++r)
#pragma unroll
                for (int c = 0; c < 2; ++c)
#pragma unroll
                    for (int ks = 0; ks < 2; ++ks)
                        acc[r][c + 2] = __builtin_amdgcn_mfma_f32_16x16x32_bf16(
                            wfB[c][ks], xfA[r][ks], acc[r][c + 2], 0, 0, 0);
            __builtin_amdgcn_s_setprio(0);
            BARRIER();

            // ---- phase 3: read xr4-7; stage W(t+2); MFMA (xr4-7 x wc0-1) ----
#pragma unroll
            for (int r = 0; r < 4; ++r)
#pragma unroll
                for (int ks = 0; ks < 2; ++ks)
                    xfB[r][ks] = ldsfrag(Xh, 64 + r * 16 + frow, ks * 64 + fkb);
            stage_half8(Wq3, bn,       NQKV - 1, kst, WsN,        tid);
            stage_half8(Wq3, bn + 128, NQKV - 1, kst, WsN + 8192, tid);
            BARRIER();
            __builtin_amdgcn_s_setprio(1);
#pragma unroll
            for (int r = 0; r < 4; ++r)
#pragma unroll
                for (int c = 0; c < 2; ++c)
#pragma unroll
                    for (int ks = 0; ks < 2; ++ks)
                        acc[r + 4][c] = __builtin_amdgcn_mfma_f32_16x16x32_bf16(
                            wfA[c][ks], xfB[r][ks], acc[r + 4][c], 0, 0, 0);
            __builtin_amdgcn_s_setprio(0);
            BARRIER();

            // ---- phase 4: stage X(t+2); MFMA (xr4-7 x wc2-3); vmcnt(8) ----
            stage_half8(X, bm,       MQKV - 1, kst, XsN,        tid);
            stage_half8(X, bm + 128, MQKV - 1, kst, XsN + 8192, tid);
            BARRIER();
            __builtin_amdgcn_s_setprio(1);
#pragma unroll
            for (int r = 0; r < 4; ++r)
#pragma unroll
                for (int c = 0; c < 2; ++c)
#pragma unroll
                    for (int ks = 0; ks < 2; ++ks)
                        acc[r + 4][c + 2] = __builtin_amdgcn_mfma_f32_16x16x32_bf16(
                            wfB[c][ks], xfB[r][ks], acc[r + 4][c + 2], 0, 0, 0);
            __builtin_amdgcn_s_setprio(0);
            VMCNT8();   // oldest stage-phase landed; next buffer safe to read
            BARRIER();
        }
    }

    // ---- epilogue: in-lane RoPE pairs + ushort4 stores ----
    const int cbase = bn + wn * 64 + ((lane >> 4) << 2);
    const int rbase = bm + wm * 128 + (lane & 15);
    const int which = bn >> 10;   // block-uniform: 0=Q 1=K 2=V

#pragma unroll
    for (int xr = 0; xr < 8; ++xr) {
        const int row = rbase + xr * 16;
        if (row >= MQKV) continue;
        const int b = row >= SS;
        const int s = row - b * SS;
#pragma unroll
        for (int wc = 0; wc < 4; ++wc) {
            const int c0 = cbase + wc * 16;
            float v0 = acc[xr][wc][0], v1 = acc[xr][wc][1];
            float v2 = acc[xr][wc][2], v3 = acc[xr][wc][3];
            const int nn = c0 & 1023;
            const int h  = nn >> 6;
            const int dh = nn & 63;
            if (which != 2 && s >= PFX) {
                const int pos = s - PFX;
                float2 cs = *reinterpret_cast<const float2*>(ropeC + pos * 32 + (dh >> 1));
                float2 sn = *reinterpret_cast<const float2*>(ropeS + pos * 32 + (dh >> 1));
                float t0 = v0 * cs.x - v1 * sn.x;
                v1 = v0 * sn.x + v1 * cs.x; v0 = t0;
                float t2 = v2 * cs.y - v3 * sn.y;
                v3 = v2 * sn.y + v3 * cs.y; v2 = t2;
            }
            ushort4 o;
            o.x = f2bf(v0); o.y = f2bf(v1); o.z = f2bf(v2); o.w = f2bf(v3);
            if (which == 0) {
                if (s >= PFX)
                    *reinterpret_cast<ushort4*>(
                        &qb[(((size_t)b * NH + h) * LL + (s - PFX)) * DHD + dh]) = o;
            } else if (which == 1) {
                *reinterpret_cast<ushort4*>(
                    &kb[(((size_t)b * NH + h) * SS + s) * DHD + dh]) = o;
            } else {
                *reinterpret_cast<ushort4*>(
                    &vb[(((size_t)b * NH + h) * SS + s) * DHD + dh]) = o;
            }
        }
    }
}

// ---------------------------------------------------------------------------
// bf16 MFMA GEMM, 128x128 tile (m97 structure) — kept for the Wo projection
// (grid 256 blocks; a 256^2 tile would idle 75% of CUs here).
// ---------------------------------------------------------------------------
__global__ __launch_bounds__(256)
void wo_gemm(const u16* __restrict__ A, const u16* __restrict__ Bw,
             float* __restrict__ outp)
{
    __shared__ short As[128 * 32] __attribute__((aligned(16)));
    __shared__ short Bs[128 * 32] __attribute__((aligned(16)));

    const int tid  = threadIdx.x;
    const int lane = tid & 63;
    const int wid  = tid >> 6;
    const int wr   = wid >> 1, wc = wid & 1;
    const int bm   = blockIdx.x * 128;
    const int bn   = blockIdx.y * 128;

    f32x4 acc[4][4];
#pragma unroll
    for (int m = 0; m < 4; ++m)
#pragma unroll
        for (int n = 0; n < 4; ++n) acc[m][n] = (f32x4)(0.f);

    const int r0 = wid * 32 + (lane >> 2);
    const int cc = (lane & 3) * 8;

    for (int k0 = 0; k0 < DIM; k0 += 32) {
        gload_lds16(A + (size_t)(bm + r0) * DIM + k0 + cc, As + wid * 1024);
        gload_lds16(A + (size_t)(bm + r0 + 16) * DIM + k0 + cc, As + wid * 1024 + 512);
        gload_lds16(Bw + (size_t)(bn + r0) * DIM + k0 + cc, Bs + wid * 1024);
        gload_lds16(Bw + (size_t)(bn + r0 + 16) * DIM + k0 + cc, Bs + wid * 1024 + 512);
        __syncthreads();

        bf16x8 wf[4], xf[4];
#pragma unroll
        for (int m = 0; m < 4; ++m)
            wf[m] = *reinterpret_cast<const bf16x8*>(
                Bs + (wr * 64 + m * 16 + (lane & 15)) * 32 + (lane >> 4) * 8);
#pragma unroll
        for (int n = 0; n < 4; ++n)
            xf[n] = *reinterpret_cast<const bf16x8*>(
                As + (wc * 64 + n * 16 + (lane & 15)) * 32 + (lane >> 4) * 8);
#pragma unroll
        for (int m = 0; m < 4; ++m)
#pragma unroll
            for (int n = 0; n < 4; ++n)
                acc[m][n] = __builtin_amdgcn_mfma_f32_16x16x32_bf16(
                    wf[m], xf[n], acc[m][n], 0, 0, 0);
        __syncthreads();
    }

    const int cbase = bn + wr * 64 + ((lane >> 4) << 2);
    const int rbase = bm + wc * 64 + (lane & 15);
#pragma unroll
    for (int n = 0; n < 4; ++n) {
        const int row = rbase + n * 16;
#pragma unroll
        for (int m = 0; m < 4; ++m) {
            const int c0 = cbase + m * 16;
            *reinterpret_cast<float4*>(&outp[(size_t)row * DIM + c0]) =
                make_float4(acc[m][n][0], acc[m][n][1], acc[m][n][2], acc[m][n][3]);
        }
    }
}

// ---------------------------------------------------------------------------
// MFMA flash attention (unchanged from round 6)
// ---------------------------------------------------------------------------
__device__ __forceinline__ void attn_load_tile(
    const u16* __restrict__ kb0, const u16* __restrict__ vb0,
    int j0, int tid, int vp, int vo,
    int4& k0r, int4& k1r, int4& v0r, int4& v1r)
{
    int key0 = tid >> 3,        o0 = tid & 7;
    int c1   = tid + 256;
    int key1 = c1 >> 3,         o1 = c1 & 7;
    int jg0 = j0 + key0; if (jg0 > SS - 1) jg0 = SS - 1;
    int jg1 = j0 + key1; if (jg1 > SS - 1) jg1 = SS - 1;
    k0r = *reinterpret_cast<const int4*>(kb0 + (size_t)jg0 * DHD + o0 * 8);
    k1r = *reinterpret_cast<const int4*>(kb0 + (size_t)jg1 * DHD + o1 * 8);
    int ja  = j0 + 2 * vp;     if (ja  > SS - 1) ja  = SS - 1;
    int jb2 = j0 + 2 * vp + 1; if (jb2 > SS - 1) jb2 = SS - 1;
    v0r = *reinterpret_cast<const int4*>(vb0 + (size_t)ja  * DHD + vo * 8);
    v1r = *reinterpret_cast<const int4*>(vb0 + (size_t)jb2 * DHD + vo * 8);
}

__global__ __launch_bounds__(256, 2)
void attn_mfma(const u16* __restrict__ qb, const u16* __restrict__ kb,
               const u16* __restrict__ vb, u16* __restrict__ ctx)
{
    __shared__ u16 Ks[64 * 64] __attribute__((aligned(16)));
    __shared__ u16 Vt[64 * 64] __attribute__((aligned(16)));
    __shared__ u16 Ot[4][32 * 72] __attribute__((aligned(16)));

    const int tid  = threadIdx.x;
    const int lane = tid & 63;
    const int wv   = tid >> 6;
    const int h    = lane >> 5;
    const int ql   = lane & 31;

    const int bh   = blockIdx.y;
    const int b    = bh >> 4;
    const int head = bh & 15;
    int qt = blockIdx.x;
    if (b) qt = 15 - qt;
    const int q0  = qt * 128;
    const int q0w = q0 + 32 * wv;

    const u16* qrow = qb + ((size_t)bh * LL + q0w + ql) * DHD;
    bf16x8 qf[4];
#pragma unroll
    for (int ks = 0; ks < 4; ++ks) {
        I4B8 t; t.i = *reinterpret_cast<const int4*>(qrow + ks * 16 + h * 8);
        qf[ks] = t.v;
    }

    f32x16 oa0 = (f32x16)(0.f), oa1 = (f32x16)(0.f);
    float m = -INFINITY, l = 0.f;

    const u16* kb0 = kb + (size_t)bh * SS * DHD;
    const u16* vb0 = vb + (size_t)bh * SS * DHD;

    const int ntiles   = (PFX + q0 + 128 + 63) / 64;
    const int wave_lim = PFX + q0w + 31;
    const int vp = tid & 31;
    const int vo = tid >> 5;

    int4 rk0, rk1, rv0, rv1;
    attn_load_tile(kb0, vb0, 0, tid, vp, vo, rk0, rk1, rv0, rv1);

    for (int kt = 0; kt < ntiles; ++kt) {
        const int j0 = kt * 64;

        {
            int key0 = tid >> 3, o0 = tid & 7;
            int c1 = tid + 256;
            int key1 = c1 >> 3, o1 = c1 & 7;
            *reinterpret_cast<int4*>((char*)Ks + ((key0 * 128 + o0 * 16) ^ ((key0 & 7) << 4))) = rk0;
            *reinterpret_cast<int4*>((char*)Ks + ((key1 * 128 + o1 * 16) ^ ((key1 & 7) << 4))) = rk1;
            const u16* pa = reinterpret_cast<const u16*>(&rv0);
            const u16* pb = reinterpret_cast<const u16*>(&rv1);
#pragma unroll
            for (int d = 0; d < 8; ++d) {
                u32 wpk = (u32)pa[d] | ((u32)pb[d] << 16);
                int dh = vo * 8 + d;
                *reinterpret_cast<u32*>((char*)Vt + ((dh * 128 + vp * 4) ^ ((d & 7) << 4))) = wpk;
            }
        }
        __syncthreads();

        int4 nk0, nk1, nv0, nv1;
        attn_load_tile(kb0, vb0, j0 + 64, tid, vp, vo, nk0, nk1, nv0, nv1);

        if (j0 <= wave_lim) {
            f32x16 s0 = (f32x16)(0.f), s1 = (f32x16)(0.f);
            __builtin_amdgcn_s_setprio(1);
#pragma unroll
            for (int ks = 0; ks < 4; ++ks) {
                I4B8 k0, k1;
                k0.i = *reinterpret_cast<const int4*>(
                    (const char*)Ks + (((ql) * 128 + ks * 32 + h * 16) ^ ((ql & 7) << 4)));
                k1.i = *reinterpret_cast<const int4*>(
                    (const char*)Ks + (((32 + ql) * 128 + ks * 32 + h * 16) ^ ((ql & 7) << 4)));
                s0 = __builtin_amdgcn_mfma_f32_32x32x16_bf16(k0.v, qf[ks], s0, 0, 0, 0);
                s1 = __builtin_amdgcn_mfma_f32_32x32x16_bf16(k1.v, qf[ks], s1, 0, 0, 0);
            }
            __builtin_amdgcn_s_setprio(0);
            float sv[32];
#pragma unroll
            for (int i = 0; i < 16; ++i) { sv[i] = s0[i] * 0.125f; sv[16 + i] = s1[i] * 0.125f; }
            if (j0 + 63 > PFX + q0w) {
                const int lim = PFX + q0w + ql - j0;
#pragma unroll
                for (int i = 0; i < 32; ++i) {
                    int koff = ((i >= 16) ? 32 : 0) + (i & 3) + 8 * ((i & 15) >> 2) + 4 * h;
                    if (koff > lim) sv[i] = -INFINITY;
                }
            }
            float mt = sv[0];
#pragma unroll
            for (int i = 1; i < 32; ++i) mt = fmaxf(mt, sv[i]);
            mt = fmaxf(mt, __shfl_xor(mt, 32));
            float mn = fmaxf(m, mt);
            float f = __expf(m - mn);
            m = mn;
            float ls = 0.f;
            u32 W0[8], W1[8];
#pragma unroll
            for (int i = 0; i < 8; ++i) {
                float pa = __expf(sv[2 * i] - m);
                float pb = __expf(sv[2 * i + 1] - m);
                ls += pa + pb;
                W0[i] = cvtpk(pa, pb);
            }
#pragma unroll
            for (int i = 0; i < 8; ++i) {
                float pa = __expf(sv[16 + 2 * i] - m);
                float pb = __expf(sv[16 + 2 * i + 1] - m);
                ls += pa + pb;
                W1[i] = cvtpk(pa, pb);
            }
            ls += __shfl_xor(ls, 32);
            l = l * f + ls;
#pragma unroll
            for (int i = 0; i < 16; ++i) { oa0[i] *= f; oa1[i] *= f; }

            __builtin_amdgcn_s_setprio(1);
#pragma unroll
            for (int ks = 0; ks < 4; ++ks) {
                const int a4 = (ks & 1) * 4;
                u32 A0, A1, A2, A3;
                if (ks < 2) { A0 = W0[a4]; A1 = W0[a4 + 1]; A2 = W0[a4 + 2]; A3 = W0[a4 + 3]; }
                else        { A0 = W1[a4]; A1 = W1[a4 + 1]; A2 = W1[a4 + 2]; A3 = W1[a4 + 3]; }
                asm volatile("v_permlane32_swap_b32 %0, %1" : "+v"(A0), "+v"(A2));
                asm volatile("v_permlane32_swap_b32 %0, %1" : "+v"(A1), "+v"(A3));
                I4B8 pf; pf.i = make_int4((int)A0, (int)A1, (int)A2, (int)A3);
                I4B8 vf0, vf1;
                vf0.i = *reinterpret_cast<const int4*>(
                    (const char*)Vt + (((ql) * 128 + ks * 32 + h * 16) ^ ((ql & 7) << 4)));
                vf1.i = *reinterpret_cast<const int4*>(
                    (const char*)Vt + (((32 + ql) * 128 + ks * 32 + h * 16) ^ ((ql & 7) << 4)));
                oa0 = __builtin_amdgcn_mfma_f32_32x32x16_bf16(vf0.v, pf.v, oa0, 0, 0, 0);
                oa1 = __builtin_amdgcn_mfma_f32_32x32x16_bf16(vf1.v, pf.v, oa1, 0, 0, 0);
            }
            __builtin_amdgcn_s_setprio(0);
        }
        __syncthreads();
        rk0 = nk0; rk1 = nk1; rv0 = nv0; rv1 = nv1;
    }

    const float inv = 1.f / l;
    u16* orow = &Ot[wv][ql * 72];
#pragma unroll
    for (int i = 0; i < 8; ++i) {
        u32 w0 = cvtpk(oa0[2 * i] * inv, oa0[2 * i + 1] * inv);
        u32 w1 = cvtpk(oa1[2 * i] * inv, oa1[2 * i + 1] * inv);
        int dh0 = ((2 * i) & 3) + 8 * ((2 * i) >> 2) + 4 * h;
        *reinterpret_cast<u32*>(&orow[dh0]) = w0;
        *reinterpret_cast<u32*>(&orow[32 + dh0]) = w1;
    }
    const int rr = lane >> 1, hh = lane & 1;
    const u16* src = &Ot[wv][rr * 72 + hh * 32];
    u16* dst = ctx + ((size_t)(b * LL + q0 + 32 * wv + rr)) * DIM + head * DHD + hh * 32;
#pragma unroll
    for (int i = 0; i < 4; ++i) {
        int4 t = *reinterpret_cast<const int4*>(src + i * 8);
        *reinterpret_cast<int4*>(dst + i * 8) = t;
    }
}

// ---------------------------------------------------------------------------
extern "C" void kernel_launch(void* const* d_in, const int* in_sizes, int n_in,
                              void* d_out, int out_size, void* d_ws, size_t ws_size,
                              hipStream_t stream)
{
    const float* x  = (const float*)d_in[0];
    const float* pe = (const float*)d_in[1];
    const float* me = (const float*)d_in[2];
    const float* Wq = (const float*)d_in[3];
    const float* Wk = (const float*)d_in[4];
    const float* Wv = (const float*)d_in[5];
    const float* Wo = (const float*)d_in[6];
    float* out = (float*)d_out;

    u16* xbf  = (u16*)d_ws;                           // 4256x1024
    u16* wqkv = xbf + (size_t)MQKV * DIM;             // 3072x1024
    u16* wobf = wqkv + (size_t)NQKV * DIM;            // 1024x1024
    float* ropeC = (float*)(wobf + (size_t)DIM * DIM);
    float* ropeS = ropeC + LL * 32;
    u16* qbf = (u16*)(ropeS + LL * 32);               // B*H*L*DH
    u16* kbf = qbf + (size_t)BB * NH * LL * DHD;      // B*H*S*DH
    u16* vbf = kbf + (size_t)BB * NH * SS * DHD;      // B*H*S*DH
    u16* ctx = vbf + (size_t)BB * NH * SS * DHD;      // B*L*DIM

    hipLaunchKernelGGL(prep_kernel, dim3(2048), dim3(256), 0, stream,
                       x, pe, me, Wq, Wk, Wv, Wo, xbf, wqkv, wobf, ropeC, ropeS);
    hipLaunchKernelGGL(qkv_gemm8, dim3((MQKV + 255) / 256, NQKV / 256), dim3(512), 0, stream,
                       xbf, wqkv, ropeC, ropeS, qbf, kbf, vbf);
    hipLaunchKernelGGL(attn_mfma, dim3(16, BB * NH), dim3(256), 0, stream,
                       qbf, kbf, vbf, ctx);
    hipLaunchKernelGGL(wo_gemm, dim3(MOUT / 128, DIM / 128), dim3(256), 0, stream,
                       ctx, wobf, out);
}

// Round 8
// 151.509 us; speedup vs baseline: 31.1087x; 1.0019x over previous
//
#include <hip/hip_runtime.h>
#include <math.h>

#define BB    2
#define LL    2048
#define DIM   1024
#define NH    16
#define DHD   64
#define NPER  16
#define NMEM  64
#define PFX   80      // NPER + NMEM
#define SS    2128    // PFX + LL
#define MQKV  (BB*SS) // 4256
#define NQKV  3072
#define MOUT  (BB*LL) // 4096

typedef __attribute__((ext_vector_type(4)))  float f32x4;
typedef __attribute__((ext_vector_type(16))) float f32x16;
typedef __attribute__((ext_vector_type(8)))  short bf16x8;
typedef unsigned short u16;
typedef unsigned int   u32;

union I4B8 { int4 i; bf16x8 v; };

__device__ __forceinline__ u16 f2bf(float x) {
    union { float f; u32 u; } v; v.f = x;
    return (u16)((v.u + 0x7fffu + ((v.u >> 16) & 1u)) >> 16);
}
__device__ __forceinline__ u32 cvtpk(float lo, float hi) {
    u32 r; asm("v_cvt_pk_bf16_f32 %0, %1, %2" : "=v"(r) : "v"(lo), "v"(hi));
    return r;
}
__device__ __forceinline__ void gload_lds16(const void* g, void* l) {
    __builtin_amdgcn_global_load_lds(
        (__attribute__((address_space(1))) void*)(g),
        (__attribute__((address_space(3))) void*)(l), 16, 0, 0);
}

// Raw barrier (NO "memory" clobber asm — that forces the waitcnt pass to
// drain vmcnt/lgkmcnt to 0 at every barrier, deleting the counted-vmcnt
// pipeline). Counted wait likewise without a clobber.
#define BARRIER()  __builtin_amdgcn_s_barrier()
#define VMCNT8()   asm volatile("s_waitcnt vmcnt(8)")

// ---------------------------------------------------------------------------
// Prep: fp32 -> bf16 conversions + RoPE tables
// ---------------------------------------------------------------------------
__global__ __launch_bounds__(256)
void prep_kernel(const float* __restrict__ x,  const float* __restrict__ pe,
                 const float* __restrict__ me, const float* __restrict__ Wq,
                 const float* __restrict__ Wk, const float* __restrict__ Wv,
                 const float* __restrict__ Wo,
                 u16* __restrict__ xbf, u16* __restrict__ wqkv,
                 u16* __restrict__ wobf,
                 float* __restrict__ ropeC, float* __restrict__ ropeS)
{
    const int nthr = gridDim.x * blockDim.x;
    const int t0   = blockIdx.x * blockDim.x + threadIdx.x;

    for (int g = t0; g < MQKV * (DIM / 4); g += nthr) {
        int d4  = g & 255;
        int row = g >> 8;
        int b   = row >= SS;
        int s   = row - b * SS;
        const float* src;
        if (s < NPER)     src = pe + ((size_t)(b * NPER + s)) * DIM;
        else if (s < PFX) src = me + ((size_t)(b * NMEM + (s - NPER))) * DIM;
        else              src = x  + ((size_t)(b * LL   + (s - PFX)))  * DIM;
        float4 v = *reinterpret_cast<const float4*>(src + d4 * 4);
        ushort4 o; o.x = f2bf(v.x); o.y = f2bf(v.y); o.z = f2bf(v.z); o.w = f2bf(v.w);
        *reinterpret_cast<ushort4*>(xbf + (size_t)g * 4) = o;
    }
    for (int g = t0; g < NQKV * (DIM / 4); g += nthr) {
        int row = g >> 8;
        const float* src = (row < 1024) ? (Wq + (size_t)row * DIM)
                         : (row < 2048) ? (Wk + (size_t)(row - 1024) * DIM)
                         :                (Wv + (size_t)(row - 2048) * DIM);
        float4 v = *reinterpret_cast<const float4*>(src + (g & 255) * 4);
        ushort4 o; o.x = f2bf(v.x); o.y = f2bf(v.y); o.z = f2bf(v.z); o.w = f2bf(v.w);
        *reinterpret_cast<ushort4*>(wqkv + (size_t)g * 4) = o;
    }
    for (int g = t0; g < DIM * (DIM / 4); g += nthr) {
        float4 v = *reinterpret_cast<const float4*>(Wo + (size_t)g * 4);
        ushort4 o; o.x = f2bf(v.x); o.y = f2bf(v.y); o.z = f2bf(v.z); o.w = f2bf(v.w);
        *reinterpret_cast<ushort4*>(wobf + (size_t)g * 4) = o;
    }
    for (int i = t0; i < LL * 32; i += nthr) {
        int pos = i >> 5, fi = i & 31;
        float ang = (float)pos * exp2f(-(float)fi * 0.41524101186092029f);
        ropeC[i] = cosf(ang);
        ropeS[i] = sinf(ang);
    }
}

// ---------------------------------------------------------------------------
// 8-phase 256x256 QKV GEMM (T2+T3+T4+T5). BK=64, 8 waves (2M x 4N),
// per-wave C = 128 x-rows x 64 w-cols. Double-buffered 128 KiB LDS.
// Swizzle: byte ^= (row&7)<<4, via pre-swizzled global source (linear
// gload_lds dest) + swizzled ds_read.  Counted vmcnt(8) at phases 4/8
// only; raw s_barrier (no vmcnt(0)/lgkmcnt(0) drain in the main loop).
// Race-freedom: W-LDS reads of a tile complete by barrier2-of-phase2,
// X-LDS reads by barrier2-of-phase3  =>  stage W(t+2) in phase 3,
// X(t+2) in phase 4.
// __launch_bounds__(512,1): LDS caps at 1 block/CU anyway; VGPR cap 512
// avoids accumulator spills (r7: cap 128 -> acc spilled to scratch).
// ---------------------------------------------------------------------------
__device__ __forceinline__ void stage_half8(const u16* __restrict__ src, int grow0,
                                            int rmax, int k0, short* ldsbase, int tid)
{
#pragma unroll
    for (int rr = 0; rr < 2; ++rr) {
        int t   = tid + rr * 512;
        int row = t >> 3;           // 0..127 within half
        int c   = t & 7;            // 16B chunk
        int g = grow0 + row; if (g > rmax) g = rmax;
        gload_lds16(src + (size_t)g * DIM + k0 + ((c ^ (row & 7)) << 3),
                    ldsbase + (tid >> 6) * 512 + rr * 4096);
    }
}

__device__ __forceinline__ bf16x8 ldsfrag(const short* hb, int row, int kbyte)
{
    int byte = (row * 128 + kbyte) ^ ((row & 7) << 4);
    I4B8 t;
    t.i = *reinterpret_cast<const int4*>(reinterpret_cast<const char*>(hb) + byte);
    return t.v;
}

__global__ __launch_bounds__(512, 1)
void qkv_gemm8(const u16* __restrict__ X, const u16* __restrict__ Wq3,
               const float* __restrict__ ropeC, const float* __restrict__ ropeS,
               u16* __restrict__ qb, u16* __restrict__ kb, u16* __restrict__ vb)
{
    __shared__ short Xs[2][16384] __attribute__((aligned(16)));
    __shared__ short Ws[2][16384] __attribute__((aligned(16)));

    const int tid  = threadIdx.x;
    const int lane = tid & 63;
    const int wid  = tid >> 6;      // 0..7
    const int wm   = wid >> 2;      // 0..1 : x-row half (128 rows)
    const int wn   = wid & 3;       // 0..3 : w-col quarter (64 cols)
    const int bm   = blockIdx.x * 256;
    const int bn   = blockIdx.y * 256;

    f32x4 acc[8][4];
#pragma unroll
    for (int r = 0; r < 8; ++r)
#pragma unroll
        for (int c = 0; c < 4; ++c) acc[r][c] = (f32x4)(0.f);

    // ---- prologue: stage tiles 0 (buf0) and 1 (buf1): 16 loads/thread ----
    stage_half8(X,   bm,       MQKV - 1, 0,  &Xs[0][0],    tid);
    stage_half8(X,   bm + 128, MQKV - 1, 0,  &Xs[0][8192], tid);
    stage_half8(Wq3, bn,       NQKV - 1, 0,  &Ws[0][0],    tid);
    stage_half8(Wq3, bn + 128, NQKV - 1, 0,  &Ws[0][8192], tid);
    stage_half8(X,   bm,       MQKV - 1, 64, &Xs[1][0],    tid);
    stage_half8(X,   bm + 128, MQKV - 1, 64, &Xs[1][8192], tid);
    stage_half8(Wq3, bn,       NQKV - 1, 64, &Ws[1][0],    tid);
    stage_half8(Wq3, bn + 128, NQKV - 1, 64, &Ws[1][8192], tid);
    VMCNT8();       // tile 0 landed (tile 1's 8 loads may remain in flight)
    BARRIER();

    const int frow = lane & 15;
    const int fkb  = (lane >> 4) * 16;     // frag k byte offset
    const int wrow = (wn & 1) * 64;        // w-row base within W half
    const short* XhA[2] = { &Xs[0][0] + wm * 8192,        &Xs[1][0] + wm * 8192 };
    const short* WhA[2] = { &Ws[0][0] + (wn >> 1) * 8192, &Ws[1][0] + (wn >> 1) * 8192 };

    for (int it = 0; it < 8; ++it) {
        int ksA = it * 128 + 128; if (ksA >= 1024) ksA = 0;    // dummy restage, harmless
        int ksB = it * 128 + 192; if (ksB >= 1024) ksB = 64;
#pragma unroll
        for (int sub = 0; sub < 2; ++sub) {
            const short* Xh = XhA[sub];
            const short* Wh = WhA[sub];
            const int kst = sub ? ksB : ksA;
            short* XsN = &Xs[sub][0];
            short* WsN = &Ws[sub][0];
            bf16x8 xfA[4][2], xfB[4][2], wfA[2][2], wfB[2][2];

            // ---- phase 1: read xr0-3 + wc0-1; MFMA (xr0-3 x wc0-1) ----
#pragma unroll
            for (int r = 0; r < 4; ++r)
#pragma unroll
                for (int ks = 0; ks < 2; ++ks)
                    xfA[r][ks] = ldsfrag(Xh, r * 16 + frow, ks * 64 + fkb);
#pragma unroll
            for (int c = 0; c < 2; ++c)
#pragma unroll
                for (int ks = 0; ks < 2; ++ks)
                    wfA[c][ks] = ldsfrag(Wh, wrow + c * 16 + frow, ks * 64 + fkb);
            BARRIER();
            __builtin_amdgcn_s_setprio(1);
#pragma unroll
            for (int r = 0; r < 4; ++r)
#pragma unroll
                for (int c = 0; c < 2; ++c)
#pragma unroll
                    for (int ks = 0; ks < 2; ++ks)
                        acc[r][c] = __builtin_amdgcn_mfma_f32_16x16x32_bf16(
                            wfA[c][ks], xfA[r][ks], acc[r][c], 0, 0, 0);
            __builtin_amdgcn_s_setprio(0);
            BARRIER();

            // ---- phase 2: read wc2-3; MFMA (xr0-3 x wc2-3) ----
#pragma unroll
            for (int c = 0; c < 2; ++c)
#pragma unroll
                for (int ks = 0; ks < 2; ++ks)
                    wfB[c][ks] = ldsfrag(Wh, wrow + 32 + c * 16 + frow, ks * 64 + fkb);
            BARRIER();
            __builtin_amdgcn_s_setprio(1);
#pragma unroll
            for (int r = 0; r < 4; ++r)
#pragma unroll
                for (int c = 0; c < 2; ++c)
#pragma unroll
                    for (int ks = 0; ks < 2; ++ks)
                        acc[r][c + 2] = __builtin_amdgcn_mfma_f32_16x16x32_bf16(
                            wfB[c][ks], xfA[r][ks], acc[r][c + 2], 0, 0, 0);
            __builtin_amdgcn_s_setprio(0);
            BARRIER();

            // ---- phase 3: read xr4-7; stage W(t+2); MFMA (xr4-7 x wc0-1) ----
#pragma unroll
            for (int r = 0; r < 4; ++r)
#pragma unroll
                for (int ks = 0; ks < 2; ++ks)
                    xfB[r][ks] = ldsfrag(Xh, 64 + r * 16 + frow, ks * 64 + fkb);
            stage_half8(Wq3, bn,       NQKV - 1, kst, WsN,        tid);
            stage_half8(Wq3, bn + 128, NQKV - 1, kst, WsN + 8192, tid);
            BARRIER();
            __builtin_amdgcn_s_setprio(1);
#pragma unroll
            for (int r = 0; r < 4; ++r)
#pragma unroll
                for (int c = 0; c < 2; ++c)
#pragma unroll
                    for (int ks = 0; ks < 2; ++ks)
                        acc[r + 4][c] = __builtin_amdgcn_mfma_f32_16x16x32_bf16(
                            wfA[c][ks], xfB[r][ks], acc[r + 4][c], 0, 0, 0);
            __builtin_amdgcn_s_setprio(0);
            BARRIER();

            // ---- phase 4: stage X(t+2); MFMA (xr4-7 x wc2-3); vmcnt(8) ----
            stage_half8(X, bm,       MQKV - 1, kst, XsN,        tid);
            stage_half8(X, bm + 128, MQKV - 1, kst, XsN + 8192, tid);
            BARRIER();
            __builtin_amdgcn_s_setprio(1);
#pragma unroll
            for (int r = 0; r < 4; ++r)
#pragma unroll
                for (int c = 0; c < 2; ++c)
#pragma unroll
                    for (int ks = 0; ks < 2; ++ks)
                        acc[r + 4][c + 2] = __builtin_amdgcn_mfma_f32_16x16x32_bf16(
                            wfB[c][ks], xfB[r][ks], acc[r + 4][c + 2], 0, 0, 0);
            __builtin_amdgcn_s_setprio(0);
            VMCNT8();   // oldest stage-phase landed; next buffer safe to read
            BARRIER();
        }
    }

    // ---- epilogue: in-lane RoPE pairs + ushort4 stores ----
    const int cbase = bn + wn * 64 + ((lane >> 4) << 2);
    const int rbase = bm + wm * 128 + (lane & 15);
    const int which = bn >> 10;   // block-uniform: 0=Q 1=K 2=V

#pragma unroll
    for (int xr = 0; xr < 8; ++xr) {
        const int row = rbase + xr * 16;
        if (row >= MQKV) continue;
        const int b = row >= SS;
        const int s = row - b * SS;
#pragma unroll
        for (int wc = 0; wc < 4; ++wc) {
            const int c0 = cbase + wc * 16;
            float v0 = acc[xr][wc][0], v1 = acc[xr][wc][1];
            float v2 = acc[xr][wc][2], v3 = acc[xr][wc][3];
            const int nn = c0 & 1023;
            const int h  = nn >> 6;
            const int dh = nn & 63;
            if (which != 2 && s >= PFX) {
                const int pos = s - PFX;
                float2 cs = *reinterpret_cast<const float2*>(ropeC + pos * 32 + (dh >> 1));
                float2 sn = *reinterpret_cast<const float2*>(ropeS + pos * 32 + (dh >> 1));
                float t0 = v0 * cs.x - v1 * sn.x;
                v1 = v0 * sn.x + v1 * cs.x; v0 = t0;
                float t2 = v2 * cs.y - v3 * sn.y;
                v3 = v2 * sn.y + v3 * cs.y; v2 = t2;
            }
            ushort4 o;
            o.x = f2bf(v0); o.y = f2bf(v1); o.z = f2bf(v2); o.w = f2bf(v3);
            if (which == 0) {
                if (s >= PFX)
                    *reinterpret_cast<ushort4*>(
                        &qb[(((size_t)b * NH + h) * LL + (s - PFX)) * DHD + dh]) = o;
            } else if (which == 1) {
                *reinterpret_cast<ushort4*>(
                    &kb[(((size_t)b * NH + h) * SS + s) * DHD + dh]) = o;
            } else {
                *reinterpret_cast<ushort4*>(
                    &vb[(((size_t)b * NH + h) * SS + s) * DHD + dh]) = o;
            }
        }
    }
}

// ---------------------------------------------------------------------------
// bf16 MFMA GEMM, 128x128 tile (m97 structure) — kept for the Wo projection
// (grid 256 blocks; a 256^2 tile would idle 75% of CUs here).
// ---------------------------------------------------------------------------
__global__ __launch_bounds__(256)
void wo_gemm(const u16* __restrict__ A, const u16* __restrict__ Bw,
             float* __restrict__ outp)
{
    __shared__ short As[128 * 32] __attribute__((aligned(16)));
    __shared__ short Bs[128 * 32] __attribute__((aligned(16)));

    const int tid  = threadIdx.x;
    const int lane = tid & 63;
    const int wid  = tid >> 6;
    const int wr   = wid >> 1, wc = wid & 1;
    const int bm   = blockIdx.x * 128;
    const int bn   = blockIdx.y * 128;

    f32x4 acc[4][4];
#pragma unroll
    for (int m = 0; m < 4; ++m)
#pragma unroll
        for (int n = 0; n < 4; ++n) acc[m][n] = (f32x4)(0.f);

    const int r0 = wid * 32 + (lane >> 2);
    const int cc = (lane & 3) * 8;

    for (int k0 = 0; k0 < DIM; k0 += 32) {
        gload_lds16(A + (size_t)(bm + r0) * DIM + k0 + cc, As + wid * 1024);
        gload_lds16(A + (size_t)(bm + r0 + 16) * DIM + k0 + cc, As + wid * 1024 + 512);
        gload_lds16(Bw + (size_t)(bn + r0) * DIM + k0 + cc, Bs + wid * 1024);
        gload_lds16(Bw + (size_t)(bn + r0 + 16) * DIM + k0 + cc, Bs + wid * 1024 + 512);
        __syncthreads();

        bf16x8 wf[4], xf[4];
#pragma unroll
        for (int m = 0; m < 4; ++m)
            wf[m] = *reinterpret_cast<const bf16x8*>(
                Bs + (wr * 64 + m * 16 + (lane & 15)) * 32 + (lane >> 4) * 8);
#pragma unroll
        for (int n = 0; n < 4; ++n)
            xf[n] = *reinterpret_cast<const bf16x8*>(
                As + (wc * 64 + n * 16 + (lane & 15)) * 32 + (lane >> 4) * 8);
#pragma unroll
        for (int m = 0; m < 4; ++m)
#pragma unroll
            for (int n = 0; n < 4; ++n)
                acc[m][n] = __builtin_amdgcn_mfma_f32_16x16x32_bf16(
                    wf[m], xf[n], acc[m][n], 0, 0, 0);
        __syncthreads();
    }

    const int cbase = bn + wr * 64 + ((lane >> 4) << 2);
    const int rbase = bm + wc * 64 + (lane & 15);
#pragma unroll
    for (int n = 0; n < 4; ++n) {
        const int row = rbase + n * 16;
#pragma unroll
        for (int m = 0; m < 4; ++m) {
            const int c0 = cbase + m * 16;
            *reinterpret_cast<float4*>(&outp[(size_t)row * DIM + c0]) =
                make_float4(acc[m][n][0], acc[m][n][1], acc[m][n][2], acc[m][n][3]);
        }
    }
}

// ---------------------------------------------------------------------------
// MFMA flash attention (unchanged from round 6)
// ---------------------------------------------------------------------------
__device__ __forceinline__ void attn_load_tile(
    const u16* __restrict__ kb0, const u16* __restrict__ vb0,
    int j0, int tid, int vp, int vo,
    int4& k0r, int4& k1r, int4& v0r, int4& v1r)
{
    int key0 = tid >> 3,        o0 = tid & 7;
    int c1   = tid + 256;
    int key1 = c1 >> 3,         o1 = c1 & 7;
    int jg0 = j0 + key0; if (jg0 > SS - 1) jg0 = SS - 1;
    int jg1 = j0 + key1; if (jg1 > SS - 1) jg1 = SS - 1;
    k0r = *reinterpret_cast<const int4*>(kb0 + (size_t)jg0 * DHD + o0 * 8);
    k1r = *reinterpret_cast<const int4*>(kb0 + (size_t)jg1 * DHD + o1 * 8);
    int ja  = j0 + 2 * vp;     if (ja  > SS - 1) ja  = SS - 1;
    int jb2 = j0 + 2 * vp + 1; if (jb2 > SS - 1) jb2 = SS - 1;
    v0r = *reinterpret_cast<const int4*>(vb0 + (size_t)ja  * DHD + vo * 8);
    v1r = *reinterpret_cast<const int4*>(vb0 + (size_t)jb2 * DHD + vo * 8);
}

__global__ __launch_bounds__(256, 2)
void attn_mfma(const u16* __restrict__ qb, const u16* __restrict__ kb,
               const u16* __restrict__ vb, u16* __restrict__ ctx)
{
    __shared__ u16 Ks[64 * 64] __attribute__((aligned(16)));
    __shared__ u16 Vt[64 * 64] __attribute__((aligned(16)));
    __shared__ u16 Ot[4][32 * 72] __attribute__((aligned(16)));

    const int tid  = threadIdx.x;
    const int lane = tid & 63;
    const int wv   = tid >> 6;
    const int h    = lane >> 5;
    const int ql   = lane & 31;

    const int bh   = blockIdx.y;
    const int b    = bh >> 4;
    const int head = bh & 15;
    int qt = blockIdx.x;
    if (b) qt = 15 - qt;
    const int q0  = qt * 128;
    const int q0w = q0 + 32 * wv;

    const u16* qrow = qb + ((size_t)bh * LL + q0w + ql) * DHD;
    bf16x8 qf[4];
#pragma unroll
    for (int ks = 0; ks < 4; ++ks) {
        I4B8 t; t.i = *reinterpret_cast<const int4*>(qrow + ks * 16 + h * 8);
        qf[ks] = t.v;
    }

    f32x16 oa0 = (f32x16)(0.f), oa1 = (f32x16)(0.f);
    float m = -INFINITY, l = 0.f;

    const u16* kb0 = kb + (size_t)bh * SS * DHD;
    const u16* vb0 = vb + (size_t)bh * SS * DHD;

    const int ntiles   = (PFX + q0 + 128 + 63) / 64;
    const int wave_lim = PFX + q0w + 31;
    const int vp = tid & 31;
    const int vo = tid >> 5;

    int4 rk0, rk1, rv0, rv1;
    attn_load_tile(kb0, vb0, 0, tid, vp, vo, rk0, rk1, rv0, rv1);

    for (int kt = 0; kt < ntiles; ++kt) {
        const int j0 = kt * 64;

        {
            int key0 = tid >> 3, o0 = tid & 7;
            int c1 = tid + 256;
            int key1 = c1 >> 3, o1 = c1 & 7;
            *reinterpret_cast<int4*>((char*)Ks + ((key0 * 128 + o0 * 16) ^ ((key0 & 7) << 4))) = rk0;
            *reinterpret_cast<int4*>((char*)Ks + ((key1 * 128 + o1 * 16) ^ ((key1 & 7) << 4))) = rk1;
            const u16* pa = reinterpret_cast<const u16*>(&rv0);
            const u16* pb = reinterpret_cast<const u16*>(&rv1);
#pragma unroll
            for (int d = 0; d < 8; ++d) {
                u32 wpk = (u32)pa[d] | ((u32)pb[d] << 16);
                int dh = vo * 8 + d;
                *reinterpret_cast<u32*>((char*)Vt + ((dh * 128 + vp * 4) ^ ((d & 7) << 4))) = wpk;
            }
        }
        __syncthreads();

        int4 nk0, nk1, nv0, nv1;
        attn_load_tile(kb0, vb0, j0 + 64, tid, vp, vo, nk0, nk1, nv0, nv1);

        if (j0 <= wave_lim) {
            f32x16 s0 = (f32x16)(0.f), s1 = (f32x16)(0.f);
            __builtin_amdgcn_s_setprio(1);
#pragma unroll
            for (int ks = 0; ks < 4; ++ks) {
                I4B8 k0, k1;
                k0.i = *reinterpret_cast<const int4*>(
                    (const char*)Ks + (((ql) * 128 + ks * 32 + h * 16) ^ ((ql & 7) << 4)));
                k1.i = *reinterpret_cast<const int4*>(
                    (const char*)Ks + (((32 + ql) * 128 + ks * 32 + h * 16) ^ ((ql & 7) << 4)));
                s0 = __builtin_amdgcn_mfma_f32_32x32x16_bf16(k0.v, qf[ks], s0, 0, 0, 0);
                s1 = __builtin_amdgcn_mfma_f32_32x32x16_bf16(k1.v, qf[ks], s1, 0, 0, 0);
            }
            __builtin_amdgcn_s_setprio(0);
            float sv[32];
#pragma unroll
            for (int i = 0; i < 16; ++i) { sv[i] = s0[i] * 0.125f; sv[16 + i] = s1[i] * 0.125f; }
            if (j0 + 63 > PFX + q0w) {
                const int lim = PFX + q0w + ql - j0;
#pragma unroll
                for (int i = 0; i < 32; ++i) {
                    int koff = ((i >= 16) ? 32 : 0) + (i & 3) + 8 * ((i & 15) >> 2) + 4 * h;
                    if (koff > lim) sv[i] = -INFINITY;
                }
            }
            float mt = sv[0];
#pragma unroll
            for (int i = 1; i < 32; ++i) mt = fmaxf(mt, sv[i]);
            mt = fmaxf(mt, __shfl_xor(mt, 32));
            float mn = fmaxf(m, mt);
            float f = __expf(m - mn);
            m = mn;
            float ls = 0.f;
            u32 W0[8], W1[8];
#pragma unroll
            for (int i = 0; i < 8; ++i) {
                float pa = __expf(sv[2 * i] - m);
                float pb = __expf(sv[2 * i + 1] - m);
                ls += pa + pb;
                W0[i] = cvtpk(pa, pb);
            }
#pragma unroll
            for (int i = 0; i < 8; ++i) {
                float pa = __expf(sv[16 + 2 * i] - m);
                float pb = __expf(sv[16 + 2 * i + 1] - m);
                ls += pa + pb;
                W1[i] = cvtpk(pa, pb);
            }
            ls += __shfl_xor(ls, 32);
            l = l * f + ls;
#pragma unroll
            for (int i = 0; i < 16; ++i) { oa0[i] *= f; oa1[i] *= f; }

            __builtin_amdgcn_s_setprio(1);
#pragma unroll
            for (int ks = 0; ks < 4; ++ks) {
                const int a4 = (ks & 1) * 4;
                u32 A0, A1, A2, A3;
                if (ks < 2) { A0 = W0[a4]; A1 = W0[a4 + 1]; A2 = W0[a4 + 2]; A3 = W0[a4 + 3]; }
                else        { A0 = W1[a4]; A1 = W1[a4 + 1]; A2 = W1[a4 + 2]; A3 = W1[a4 + 3]; }
                asm volatile("v_permlane32_swap_b32 %0, %1" : "+v"(A0), "+v"(A2));
                asm volatile("v_permlane32_swap_b32 %0, %1" : "+v"(A1), "+v"(A3));
                I4B8 pf; pf.i = make_int4((int)A0, (int)A1, (int)A2, (int)A3);
                I4B8 vf0, vf1;
                vf0.i = *reinterpret_cast<const int4*>(
                    (const char*)Vt + (((ql) * 128 + ks * 32 + h * 16) ^ ((ql & 7) << 4)));
                vf1.i = *reinterpret_cast<const int4*>(
                    (const char*)Vt + (((32 + ql) * 128 + ks * 32 + h * 16) ^ ((ql & 7) << 4)));
                oa0 = __builtin_amdgcn_mfma_f32_32x32x16_bf16(vf0.v, pf.v, oa0, 0, 0, 0);
                oa1 = __builtin_amdgcn_mfma_f32_32x32x16_bf16(vf1.v, pf.v, oa1, 0, 0, 0);
            }
            __builtin_amdgcn_s_setprio(0);
        }
        __syncthreads();
        rk0 = nk0; rk1 = nk1; rv0 = nv0; rv1 = nv1;
    }

    const float inv = 1.f / l;
    u16* orow = &Ot[wv][ql * 72];
#pragma unroll
    for (int i = 0; i < 8; ++i) {
        u32 w0 = cvtpk(oa0[2 * i] * inv, oa0[2 * i + 1] * inv);
        u32 w1 = cvtpk(oa1[2 * i] * inv, oa1[2 * i + 1] * inv);
        int dh0 = ((2 * i) & 3) + 8 * ((2 * i) >> 2) + 4 * h;
        *reinterpret_cast<u32*>(&orow[dh0]) = w0;
        *reinterpret_cast<u32*>(&orow[32 + dh0]) = w1;
    }
    const int rr = lane >> 1, hh = lane & 1;
    const u16* src = &Ot[wv][rr * 72 + hh * 32];
    u16* dst = ctx + ((size_t)(b * LL + q0 + 32 * wv + rr)) * DIM + head * DHD + hh * 32;
#pragma unroll
    for (int i = 0; i < 4; ++i) {
        int4 t = *reinterpret_cast<const int4*>(src + i * 8);
        *reinterpret_cast<int4*>(dst + i * 8) = t;
    }
}

// ---------------------------------------------------------------------------
extern "C" void kernel_launch(void* const* d_in, const int* in_sizes, int n_in,
                              void* d_out, int out_size, void* d_ws, size_t ws_size,
                              hipStream_t stream)
{
    const float* x  = (const float*)d_in[0];
    const float* pe = (const float*)d_in[1];
    const float* me = (const float*)d_in[2];
    const float* Wq = (const float*)d_in[3];
    const float* Wk = (const float*)d_in[4];
    const float* Wv = (const float*)d_in[5];
    const float* Wo = (const float*)d_in[6];
    float* out = (float*)d_out;

    u16* xbf  = (u16*)d_ws;                           // 4256x1024
    u16* wqkv = xbf + (size_t)MQKV * DIM;             // 3072x1024
    u16* wobf = wqkv + (size_t)NQKV * DIM;            // 1024x1024
    float* ropeC = (float*)(wobf + (size_t)DIM * DIM);
    float* ropeS = ropeC + LL * 32;
    u16* qbf = (u16*)(ropeS + LL * 32);               // B*H*L*DH
    u16* kbf = qbf + (size_t)BB * NH * LL * DHD;      // B*H*S*DH
    u16* vbf = kbf + (size_t)BB * NH * SS * DHD;      // B*H*S*DH
    u16* ctx = vbf + (size_t)BB * NH * SS * DHD;      // B*L*DIM

    hipLaunchKernelGGL(prep_kernel, dim3(2048), dim3(256), 0, stream,
                       x, pe, me, Wq, Wk, Wv, Wo, xbf, wqkv, wobf, ropeC, ropeS);
    hipLaunchKernelGGL(qkv_gemm8, dim3((MQKV + 255) / 256, NQKV / 256), dim3(512), 0, stream,
                       xbf, wqkv, ropeC, ropeS, qbf, kbf, vbf);
    hipLaunchKernelGGL(attn_mfma, dim3(16, BB * NH), dim3(256), 0, stream,
                       qbf, kbf, vbf, ctx);
    hipLaunchKernelGGL(wo_gemm, dim3(MOUT / 128, DIM / 128), dim3(256), 0, stream,
                       ctx, wobf, out);
}